// Round 2
// baseline (648.203 us; speedup 1.0000x reference)
//
#include <hip/hip_runtime.h>
#include <hip/hip_bf16.h>
#include <hip/hip_cooperative_groups.h>

namespace cg = cooperative_groups;

namespace {

constexpr int B = 4;
constexpr int N = 8192;     // 2^13
constexpr int D = 16;
constexpr int R = 32;
constexpr int H = 64;
constexpr int E = 262144;   // 2^18

typedef __attribute__((ext_vector_type(8))) short short8;   // 8 x bf16 (4 VGPRs)
typedef __attribute__((ext_vector_type(4))) short short4v;  // 4 x bf16 (2 VGPRs)
typedef __attribute__((ext_vector_type(4))) float f32x4;    // MFMA accumulator

__device__ __forceinline__ float4 ld4(const float* p) {
    return *reinterpret_cast<const float4*>(p);
}
__device__ __forceinline__ float4 fma4(float a, float4 w, float4 c) {
    return float4{fmaf(a, w.x, c.x), fmaf(a, w.y, c.y),
                  fmaf(a, w.z, c.z), fmaf(a, w.w, c.w)};
}
__device__ __forceinline__ float4 relu4(float4 v) {
    return float4{fmaxf(v.x, 0.f), fmaxf(v.y, 0.f), fmaxf(v.z, 0.f), fmaxf(v.w, 0.f)};
}
__device__ __forceinline__ short bf16s(float f) {
    __hip_bfloat16 h = __float2bfloat16(f);   // RNE
    return __builtin_bit_cast(short, h);
}
__device__ __forceinline__ short8 pack8(float4 a, float4 b) {
    short8 o;
    o[0] = bf16s(a.x); o[1] = bf16s(a.y); o[2] = bf16s(a.z); o[3] = bf16s(a.w);
    o[4] = bf16s(b.x); o[5] = bf16s(b.y); o[6] = bf16s(b.z); o[7] = bf16s(b.w);
    return o;
}
// relu + pack 4 accumulator floats into 4 bf16 (one ds_write_b64)
__device__ __forceinline__ short4v pack4_relu(f32x4 c) {
    short4v o;
    o[0] = bf16s(fmaxf(c[0], 0.f)); o[1] = bf16s(fmaxf(c[1], 0.f));
    o[2] = bf16s(fmaxf(c[2], 0.f)); o[3] = bf16s(fmaxf(c[3], 0.f));
    return o;
}
// extract position i (0..31) from 4x int4 of packed bf16 (i must be compile-time)
__device__ __forceinline__ float red_get(const int4* uu, int i) {
    const int wsel = i >> 1;
    const int4 v = uu[wsel >> 2];
    const int word = (wsel & 3) == 0 ? v.x : (wsel & 3) == 1 ? v.y
                   : (wsel & 3) == 2 ? v.z : v.w;
    return (i & 1) ? __builtin_bit_cast(float, word & 0xffff0000)
                   : __builtin_bit_cast(float, (unsigned)word << 16);
}

constexpr int RED_S = 264;   // red stride in shorts; %8==0 keeps b128 reads 16B-aligned

__device__ __forceinline__ void prepack_w12(
    int t, const float* __restrict__ W1, const float* __restrict__ W2,
    short* __restrict__ w1p, short* __restrict__ w2p)
{
    // A/B-frag mapping (mfma_f32_16x16x32_bf16, verified m89):
    //   m|n = lane&15, k = (lane>>4)*8 + j  (identical for A and B)
    for (int i = t; i < 4 * 64 * 8; i += 256) {
        int j = i & 7, lane = (i >> 3) & 63, ct = i >> 9;
        int k = (lane >> 4) * 8 + j, n = ct * 16 + (lane & 15);
        w1p[i] = bf16s(W1[k * H + n]);
    }
    for (int i = t; i < 4 * 64 * 8; i += 256) {
        int j = i & 7, lane = (i >> 3) & 63, idx = i >> 9;
        int ct = idx >> 1, kc = idx & 1;
        int k = kc * 32 + (lane >> 4) * 8 + j, f = ct * 16 + (lane & 15);
        w2p[i] = bf16s(W2[k * R + f]);
    }
}
__device__ __forceinline__ void prepack_w34(
    int t, const float* __restrict__ W3, const float* __restrict__ W4,
    short* __restrict__ w3p, short* __restrict__ w4p)
{
    for (int i = t; i < 8 * 64 * 8; i += 256) {
        int j = i & 7, lane = (i >> 3) & 63, idx = i >> 9;
        int ct = idx >> 1, kc = idx & 1;
        int k = kc * 32 + (lane >> 4) * 8 + j, n = ct * 16 + (lane & 15);
        w3p[i] = (k < D + R) ? bf16s(W3[k * H + n]) : (short)0;
    }
    for (int i = t; i < 2 * 64 * 8; i += 256) {
        int j = i & 7, lane = (i >> 3) & 63, kc = i >> 9;
        int k = kc * 32 + (lane >> 4) * 8 + j, d = lane & 15;
        w4p[i] = bf16s(W4[k * D + d]);
    }
}

struct Params {
    const float* particles;
    const int*   senders;
    const int*   receivers;
    const float* W1; const float* b1;
    const float* W2; const float* b2;
    const float* W3; const float* b3;
    const float* W4; const float* b4;
    int*   cnt;
    int*   pos;
    int2*  sr;
    float* rel;
    short* w1p; short* w2p; short* w3p; short* w4p;
    float* out;
};

// ---------------------------------------------------------------------------
// One cooperative kernel for the whole fast path. Grid-stride in every phase
// so ANY grid size works; host sizes the grid from the occupancy query and
// falls back to the proven multi-dispatch path if the coop launch is refused.
// ---------------------------------------------------------------------------
__global__ __launch_bounds__(256, 4) void fused_kernel(Params p) {
    __shared__ short red[R * RED_S];          // [f][pos] bf16, stride 264 (16.9 KB)
    __shared__ short hbuf[4][16 * 72];        // per-wave [edge][hidden], stride 72
    __shared__ int   rs[256];                 // receivers of current chunk

    const int tid  = threadIdx.x;
    const int bid  = blockIdx.x;
    const int g    = (int)gridDim.x;
    const int gstr = g * 256;
    const int gtid = bid * 256 + tid;
    const int lane = tid & 63;
    const int w    = tid >> 6;
    const int l15  = lane & 15;
    const int q    = lane >> 4;

    cg::grid_group grid = cg::this_grid();

    // ---- P0: zero cnt + rel, prepack weights ----
    for (int i = gtid; i < N; i += gstr) p.cnt[i] = 0;
    for (int i = gtid; i < (B * N * R) / 4; i += gstr)
        reinterpret_cast<float4*>(p.rel)[i] = float4{0.f, 0.f, 0.f, 0.f};
    if (bid == 0) prepack_w12(tid, p.W1, p.W2, p.w1p, p.w2p);
    if (bid == (g > 1 ? 1 : 0)) prepack_w34(tid, p.W3, p.W4, p.w3p, p.w4p);
    __threadfence();
    grid.sync();

    // ---- P1: receiver histogram ----
    for (int i = gtid; i < E; i += gstr) atomicAdd(p.cnt + p.receivers[i], 1);
    __threadfence();
    grid.sync();

    // ---- P2: exclusive scan of 8192 counts (block 0, 32 counts/thread) ----
    if (bid == 0) {
        int4 c[8];
        const int4* c4 = reinterpret_cast<const int4*>(p.cnt) + tid * 8;
        #pragma unroll
        for (int i = 0; i < 8; ++i) c[i] = c4[i];
        int s = 0;
        #pragma unroll
        for (int i = 0; i < 8; ++i) s += c[i].x + c[i].y + c[i].z + c[i].w;
        int incl = s;
        #pragma unroll
        for (int d = 1; d < 64; d <<= 1) {
            int v = __shfl_up(incl, d, 64);
            if (lane >= d) incl += v;
        }
        if (lane == 63) rs[w] = incl;          // rs reused as per-wave totals
        __syncthreads();
        int base = incl - s;
        #pragma unroll
        for (int i = 0; i < 4; ++i) base += (i < w) ? rs[i] : 0;
        int4* po = reinterpret_cast<int4*>(p.pos) + tid * 8;
        #pragma unroll
        for (int i = 0; i < 8; ++i) {
            int4 cv = c[i];
            int4 o;
            o.x = base; base += cv.x;
            o.y = base; base += cv.y;
            o.z = base; base += cv.z;
            o.w = base; base += cv.w;
            po[i] = o;
        }
    }
    __threadfence();
    grid.sync();

    // ---- P3: scatter edges into receiver-sorted order ----
    for (int i = gtid; i < E; i += gstr) {
        const int r  = p.receivers[i];
        const int s  = p.senders[i];
        const int pp = atomicAdd(p.pos + r, 1);
        p.sr[pp] = int2{s, r};
    }
    __threadfence();
    grid.sync();

    // ---- P4: edge MLP + segmented reduction; chunk-strided, 4 batches/chunk ----
    {
        // weight fragments + biases: chunk- and batch-invariant, loaded once
        short8 w1f[4], w2f[4];
        #pragma unroll
        for (int mt = 0; mt < 4; ++mt)
            w1f[mt] = *reinterpret_cast<const short8*>(p.w1p + (mt * 64 + lane) * 8);
        #pragma unroll
        for (int i = 0; i < 4; ++i)
            w2f[i] = *reinterpret_cast<const short8*>(p.w2p + (i * 64 + lane) * 8);
        f32x4 bias1[4];
        #pragma unroll
        for (int mt = 0; mt < 4; ++mt) {
            float4 t4 = ld4(p.b1 + mt * 16 + q * 4);
            bias1[mt] = f32x4{t4.x, t4.y, t4.z, t4.w};
        }
        const float bias2a = p.b2[l15];
        const float bias2b = p.b2[16 + l15];

        const int g2 = tid >> 5;
        const int f  = tid & 31;
        const int gb = g2 * 32;

        short* hb = &hbuf[w][0];

        for (int c = bid; c < E / 256; c += g) {
            const int2 srv = p.sr[c * 256 + tid];
            __syncthreads();                 // prev chunk's rs/red readers done
            rs[tid] = srv.y;

            // row offsets (batch-invariant): distribute via shfl
            int off[4];
            #pragma unroll
            for (int t = 0; t < 4; ++t) {
                const int srow = __shfl(srv.x, t * 16 + l15);
                const int rrow = __shfl(srv.y, t * 16 + l15);
                off[t] = ((q < 2) ? srow : rrow) * D + (q & 1) * 8;
            }
            __syncthreads();                 // rs visible block-wide

            // segment-boundary mask for this (group, feature) -- batch-invariant
            unsigned bmask = 0;
            int first;
            {
                int4 r4[8];
                #pragma unroll
                for (int i = 0; i < 8; ++i)
                    r4[i] = *reinterpret_cast<const int4*>(rs + gb + 4 * i);
                first = r4[0].x;
                int prev = first;
                #pragma unroll
                for (int i = 1; i < 32; ++i) {
                    const int4 v4 = r4[i >> 2];
                    const int rr = (i & 3) == 0 ? v4.x : (i & 3) == 1 ? v4.y
                                 : (i & 3) == 2 ? v4.z : v4.w;
                    if (rr != prev) bmask |= (1u << i);
                    prev = rr;
                }
            }

            // gather batch 0
            float4 g0[4], g1[4];
            #pragma unroll
            for (int t = 0; t < 4; ++t) {
                const float* s0 = p.particles + off[t];
                g0[t] = ld4(s0);
                g1[t] = ld4(s0 + 4);
            }

            #pragma unroll 1
            for (int b = 0; b < 4; ++b) {
                short8 af[4];
                #pragma unroll
                for (int t = 0; t < 4; ++t) af[t] = pack8(g0[t], g1[t]);
                if (b < 3) {   // prefetch next batch under this batch's compute
                    const float* nb = p.particles + (size_t)(b + 1) * N * D;
                    #pragma unroll
                    for (int t = 0; t < 4; ++t) {
                        g0[t] = ld4(nb + off[t]);
                        g1[t] = ld4(nb + off[t] + 4);
                    }
                }

                #pragma unroll
                for (int t = 0; t < 4; ++t) {
                    // layer1: 4 hidden m-tiles, K=32; XOR-swizzled tile slot
                    #pragma unroll
                    for (int mt = 0; mt < 4; ++mt) {
                        f32x4 cc = bias1[mt];
                        cc = __builtin_amdgcn_mfma_f32_16x16x32_bf16(w1f[mt], af[t], cc, 0, 0, 0);
                        const int smt = (mt + l15) & 3;
                        *reinterpret_cast<short4v*>(hb + l15 * 72 + smt * 16 + q * 4) = pack4_relu(cc);
                    }
                    const int sm0 = ((q >> 1) + l15) & 3;
                    const int sm1 = (2 + (q >> 1) + l15) & 3;
                    short8 h0 = *reinterpret_cast<const short8*>(hb + l15 * 72 + sm0 * 16 + (q & 1) * 8);
                    short8 h1 = *reinterpret_cast<const short8*>(hb + l15 * 72 + sm1 * 16 + (q & 1) * 8);

                    // layer2: D2[edge][f], 2 f-tiles, K=64
                    f32x4 r0 = {bias2a, bias2a, bias2a, bias2a};
                    f32x4 r1 = {bias2b, bias2b, bias2b, bias2b};
                    r0 = __builtin_amdgcn_mfma_f32_16x16x32_bf16(h0, w2f[0], r0, 0, 0, 0);
                    r0 = __builtin_amdgcn_mfma_f32_16x16x32_bf16(h1, w2f[1], r0, 0, 0, 0);
                    r1 = __builtin_amdgcn_mfma_f32_16x16x32_bf16(h0, w2f[2], r1, 0, 0, 0);
                    r1 = __builtin_amdgcn_mfma_f32_16x16x32_bf16(h1, w2f[3], r1, 0, 0, 0);

                    const int pb2 = w * 64 + t * 16 + q * 4;
                    *reinterpret_cast<short4v*>(red + l15 * RED_S + pb2)        = pack4_relu(r0);
                    *reinterpret_cast<short4v*>(red + (16 + l15) * RED_S + pb2) = pack4_relu(r1);
                }
                __syncthreads();

                // segmented reduction for batch b
                int4 uu[4];
                #pragma unroll
                for (int i = 0; i < 4; ++i)
                    uu[i] = *reinterpret_cast<const int4*>(red + f * RED_S + gb + 8 * i);
                float* relb = p.rel + (size_t)b * N * R;
                if (bmask == 0) {
                    float acc = 0.f;
                    #pragma unroll
                    for (int i = 0; i < 32; ++i) acc += red_get(uu, i);
                    atomicAdd(relb + (size_t)first * R + f, acc);
                } else {
                    float acc = 0.f;
                    int cur = first;
                    #pragma unroll
                    for (int i = 0; i < 32; ++i) {
                        if (bmask & (1u << i)) {
                            atomicAdd(relb + (size_t)cur * R + f, acc);
                            acc = 0.f;
                            cur = rs[gb + i];
                        }
                        acc += red_get(uu, i);
                    }
                    atomicAdd(relb + (size_t)cur * R + f, acc);
                }
                if (b < 3) __syncthreads();   // red reused next batch
            }
        }
    }
    __threadfence();
    grid.sync();

    // ---- P5: node MLP (2048 tiles; tile-strided, all 4 waves) ----
    {
        short8 w3f[8], w4f[2];
        #pragma unroll
        for (int i = 0; i < 8; ++i)
            w3f[i] = *reinterpret_cast<const short8*>(p.w3p + (i * 64 + lane) * 8);
        #pragma unroll
        for (int i = 0; i < 2; ++i)
            w4f[i] = *reinterpret_cast<const short8*>(p.w4p + (i * 64 + lane) * 8);
        f32x4 bias3[4];
        #pragma unroll
        for (int mt = 0; mt < 4; ++mt) {
            float4 t4 = ld4(p.b3 + mt * 16 + q * 4);
            bias3[mt] = f32x4{t4.x, t4.y, t4.z, t4.w};
        }
        f32x4 bias4;
        { float4 t4 = ld4(p.b4 + q * 4); bias4 = f32x4{t4.x, t4.y, t4.z, t4.w}; }

        short* hb = &hbuf[w][0];
        for (int tile = bid * 4 + w; tile < (B * N) / 16; tile += g * 4) {
            const int b    = tile >> 9;                 // 512 tiles per batch
            const int node = (tile & 511) * 16 + l15;

            const float* prow = p.particles + ((size_t)b * N + node) * D;
            const float* rrow = p.rel + ((size_t)b * N + node) * R;

            const float* src0 = (q < 2) ? (prow + (q & 1) * 8) : (rrow + (q & 1) * 8);
            float4 c0a = ld4(src0), c0b = ld4(src0 + 4);
            float4 c1a = {0.f, 0.f, 0.f, 0.f}, c1b = {0.f, 0.f, 0.f, 0.f};
            if (q < 2) { c1a = ld4(rrow + 16 + q * 8); c1b = ld4(rrow + 20 + q * 8); }

            short8 a0 = pack8(c0a, c0b);
            short8 a1 = pack8(c1a, c1b);

            #pragma unroll
            for (int mt = 0; mt < 4; ++mt) {
                f32x4 cc = bias3[mt];
                cc = __builtin_amdgcn_mfma_f32_16x16x32_bf16(w3f[mt * 2 + 0], a0, cc, 0, 0, 0);
                cc = __builtin_amdgcn_mfma_f32_16x16x32_bf16(w3f[mt * 2 + 1], a1, cc, 0, 0, 0);
                *reinterpret_cast<short4v*>(hb + l15 * 72 + mt * 16 + q * 4) = pack4_relu(cc);
            }
            short8 h0 = *reinterpret_cast<const short8*>(hb + l15 * 72 + q * 8);
            short8 h1 = *reinterpret_cast<const short8*>(hb + l15 * 72 + 32 + q * 8);

            f32x4 r = bias4;
            r = __builtin_amdgcn_mfma_f32_16x16x32_bf16(w4f[0], h0, r, 0, 0, 0);
            r = __builtin_amdgcn_mfma_f32_16x16x32_bf16(w4f[1], h1, r, 0, 0, 0);

            float4 pv = ld4(prow + q * 4);
            float4* po = reinterpret_cast<float4*>(p.out + ((size_t)b * N + node) * D + q * 4);
            *po = float4{pv.x + r[0], pv.y + r[1], pv.z + r[2], pv.w + r[3]};
        }
    }
}

// ---------- proven multi-dispatch fast path (fallback if coop refused) ----------

__global__ __launch_bounds__(256) void hist_prepack_kernel(
    const int* __restrict__ receivers, int* __restrict__ cnt,
    const float* __restrict__ W1, const float* __restrict__ W2,
    const float* __restrict__ W3, const float* __restrict__ W4,
    short* __restrict__ w1p, short* __restrict__ w2p,
    short* __restrict__ w3p, short* __restrict__ w4p,
    float4* __restrict__ relz)
{
    if (blockIdx.x < 1024) {
        int e = blockIdx.x * 256 + threadIdx.x;
        atomicAdd(cnt + receivers[e], 1);
        return;
    }
    if (blockIdx.x >= 1025) {
        const int base = (blockIdx.x - 1025) * 256 + threadIdx.x;
        #pragma unroll
        for (int i = 0; i < 8; ++i)
            relz[base + i * 32768] = float4{0.f, 0.f, 0.f, 0.f};
        return;
    }
    prepack_w12(threadIdx.x, W1, W2, w1p, w2p);
    prepack_w34(threadIdx.x, W3, W4, w3p, w4p);
}

__global__ __launch_bounds__(1024) void scan_kernel(
    const int* __restrict__ cnt, int* __restrict__ pos)
{
    __shared__ int wtot[16];
    const int t = threadIdx.x;
    const int lane = t & 63;
    int local[8];
    int s = 0;
    #pragma unroll
    for (int i = 0; i < 8; ++i) { local[i] = cnt[t * 8 + i]; s += local[i]; }
    int incl = s;
    #pragma unroll
    for (int d = 1; d < 64; d <<= 1) {
        int v = __shfl_up(incl, d, 64);
        if (lane >= d) incl += v;
    }
    if (lane == 63) wtot[t >> 6] = incl;
    __syncthreads();
    int base = incl - s;
    const int wv = t >> 6;
    #pragma unroll
    for (int i = 0; i < 16; ++i) base += (i < wv) ? wtot[i] : 0;
    #pragma unroll
    for (int i = 0; i < 8; ++i) {
        pos[t * 8 + i] = base;
        base += local[i];
    }
}

__global__ __launch_bounds__(256) void scatter_kernel(
    const int* __restrict__ senders, const int* __restrict__ receivers,
    int* __restrict__ pos, int2* __restrict__ sr)
{
    int e = blockIdx.x * 256 + threadIdx.x;
    if (e < E) {
        int r = receivers[e];
        int p = atomicAdd(pos + r, 1);
        sr[p] = int2{senders[e], r};
    }
}

__global__ __launch_bounds__(256, 4) void edge_mfma_kernel(
    const float* __restrict__ particles,
    const int2*  __restrict__ sr,
    const short* __restrict__ w1p, const float* __restrict__ b1,
    const short* __restrict__ w2p, const float* __restrict__ b2,
    float* __restrict__ rel)
{
    __shared__ short red[R * RED_S];
    __shared__ short hbuf[4][16 * 72];
    __shared__ int   rs[256];

    const int tid  = threadIdx.x;
    const int lane = tid & 63;
    const int w    = tid >> 6;
    const int b    = blockIdx.x >> 10;
    const int p0   = (blockIdx.x & 1023) * 256;
    const int l15  = lane & 15;
    const int q    = lane >> 4;

    const int2 srv = sr[p0 + tid];
    rs[tid] = srv.y;

    float4 a0[4], a1[4];
    #pragma unroll
    for (int t = 0; t < 4; ++t) {
        int srow = __shfl(srv.x, t * 16 + l15);
        int rrow = __shfl(srv.y, t * 16 + l15);
        int row = (q < 2) ? srow : rrow;
        const float* src = particles + ((size_t)b * N + row) * D + (q & 1) * 8;
        a0[t] = ld4(src);
        a1[t] = ld4(src + 4);
    }

    short8 w1f[4], w2f[4];
    #pragma unroll
    for (int mt = 0; mt < 4; ++mt)
        w1f[mt] = *reinterpret_cast<const short8*>(w1p + (mt * 64 + lane) * 8);
    #pragma unroll
    for (int i = 0; i < 4; ++i)
        w2f[i] = *reinterpret_cast<const short8*>(w2p + (i * 64 + lane) * 8);

    f32x4 bias1[4];
    #pragma unroll
    for (int mt = 0; mt < 4; ++mt) {
        float4 t4 = ld4(b1 + mt * 16 + q * 4);
        bias1[mt] = f32x4{t4.x, t4.y, t4.z, t4.w};
    }
    const float bias2a = b2[l15];
    const float bias2b = b2[16 + l15];

    short8 af[4];
    #pragma unroll
    for (int t = 0; t < 4; ++t) af[t] = pack8(a0[t], a1[t]);

    short* hb = &hbuf[w][0];

    #pragma unroll
    for (int t = 0; t < 4; ++t) {
        #pragma unroll
        for (int mt = 0; mt < 4; ++mt) {
            f32x4 c = bias1[mt];
            c = __builtin_amdgcn_mfma_f32_16x16x32_bf16(w1f[mt], af[t], c, 0, 0, 0);
            const int smt = (mt + l15) & 3;
            *reinterpret_cast<short4v*>(hb + l15 * 72 + smt * 16 + q * 4) = pack4_relu(c);
        }
        const int sm0 = ((q >> 1) + l15) & 3;
        const int sm1 = (2 + (q >> 1) + l15) & 3;
        short8 h0 = *reinterpret_cast<const short8*>(hb + l15 * 72 + sm0 * 16 + (q & 1) * 8);
        short8 h1 = *reinterpret_cast<const short8*>(hb + l15 * 72 + sm1 * 16 + (q & 1) * 8);

        f32x4 r0 = {bias2a, bias2a, bias2a, bias2a};
        f32x4 r1 = {bias2b, bias2b, bias2b, bias2b};
        r0 = __builtin_amdgcn_mfma_f32_16x16x32_bf16(h0, w2f[0], r0, 0, 0, 0);
        r0 = __builtin_amdgcn_mfma_f32_16x16x32_bf16(h1, w2f[1], r0, 0, 0, 0);
        r1 = __builtin_amdgcn_mfma_f32_16x16x32_bf16(h0, w2f[2], r1, 0, 0, 0);
        r1 = __builtin_amdgcn_mfma_f32_16x16x32_bf16(h1, w2f[3], r1, 0, 0, 0);

        const int pb2 = w * 64 + t * 16 + q * 4;
        *reinterpret_cast<short4v*>(red + l15 * RED_S + pb2)        = pack4_relu(r0);
        *reinterpret_cast<short4v*>(red + (16 + l15) * RED_S + pb2) = pack4_relu(r1);
    }
    __syncthreads();

    const int g = tid >> 5;
    const int f = tid & 31;
    const int base = g * 32;

    int4 uu[4];
    #pragma unroll
    for (int i = 0; i < 4; ++i)
        uu[i] = *reinterpret_cast<const int4*>(red + f * RED_S + base + 8 * i);
    int4 r4[8];
    #pragma unroll
    for (int i = 0; i < 8; ++i)
        r4[i] = *reinterpret_cast<const int4*>(rs + base + 4 * i);

    const int first = r4[0].x;
    const int last  = r4[7].w;
    if (first == last) {
        float acc = 0.f;
        #pragma unroll
        for (int i = 0; i < 32; ++i) acc += red_get(uu, i);
        atomicAdd(rel + ((size_t)b * N + first) * R + f, acc);
    } else {
        float acc = 0.f;
        int cur = first;
        #pragma unroll
        for (int i = 0; i < 32; ++i) {
            int rr = (i & 3) == 0 ? r4[i >> 2].x : (i & 3) == 1 ? r4[i >> 2].y
                   : (i & 3) == 2 ? r4[i >> 2].z : r4[i >> 2].w;
            float v = red_get(uu, i);
            if (rr != cur) {
                atomicAdd(rel + ((size_t)b * N + cur) * R + f, acc);
                acc = 0.f;
                cur = rr;
            }
            acc += v;
        }
        atomicAdd(rel + ((size_t)b * N + cur) * R + f, acc);
    }
}

__global__ __launch_bounds__(256, 4) void node_mfma_kernel(
    const float* __restrict__ particles,
    const float* __restrict__ rel,
    const short* __restrict__ w3p, const float* __restrict__ b3,
    const short* __restrict__ w4p, const float* __restrict__ b4,
    float* __restrict__ out)
{
    __shared__ short hbuf[4][16 * 72];

    const int tid  = threadIdx.x;
    const int lane = tid & 63;
    const int w    = tid >> 6;
    const int tile = blockIdx.x * 4 + w;
    const int b    = tile >> 9;
    const int l15  = lane & 15;
    const int q    = lane >> 4;
    const int node = (tile & 511) * 16 + l15;

    const float* prow = particles + ((size_t)b * N + node) * D;
    const float* rrow = rel + ((size_t)b * N + node) * R;

    const float* src0 = (q < 2) ? (prow + (q & 1) * 8) : (rrow + (q & 1) * 8);
    float4 c0a = ld4(src0), c0b = ld4(src0 + 4);
    float4 c1a = {0.f, 0.f, 0.f, 0.f}, c1b = {0.f, 0.f, 0.f, 0.f};
    if (q < 2) { c1a = ld4(rrow + 16 + q * 8); c1b = ld4(rrow + 20 + q * 8); }

    short8 w3f[8], w4f[2];
    #pragma unroll
    for (int i = 0; i < 8; ++i)
        w3f[i] = *reinterpret_cast<const short8*>(w3p + (i * 64 + lane) * 8);
    #pragma unroll
    for (int i = 0; i < 2; ++i)
        w4f[i] = *reinterpret_cast<const short8*>(w4p + (i * 64 + lane) * 8);

    f32x4 bias3[4];
    #pragma unroll
    for (int mt = 0; mt < 4; ++mt) {
        float4 t4 = ld4(b3 + mt * 16 + q * 4);
        bias3[mt] = f32x4{t4.x, t4.y, t4.z, t4.w};
    }
    f32x4 bias4;
    { float4 t4 = ld4(b4 + q * 4); bias4 = f32x4{t4.x, t4.y, t4.z, t4.w}; }

    short8 a0 = pack8(c0a, c0b);
    short8 a1 = pack8(c1a, c1b);

    short* hb = &hbuf[w][0];
    #pragma unroll
    for (int mt = 0; mt < 4; ++mt) {
        f32x4 c = bias3[mt];
        c = __builtin_amdgcn_mfma_f32_16x16x32_bf16(w3f[mt * 2 + 0], a0, c, 0, 0, 0);
        c = __builtin_amdgcn_mfma_f32_16x16x32_bf16(w3f[mt * 2 + 1], a1, c, 0, 0, 0);
        *reinterpret_cast<short4v*>(hb + l15 * 72 + mt * 16 + q * 4) = pack4_relu(c);
    }
    short8 h0 = *reinterpret_cast<const short8*>(hb + l15 * 72 + q * 8);
    short8 h1 = *reinterpret_cast<const short8*>(hb + l15 * 72 + 32 + q * 8);

    f32x4 r = bias4;
    r = __builtin_amdgcn_mfma_f32_16x16x32_bf16(w4f[0], h0, r, 0, 0, 0);
    r = __builtin_amdgcn_mfma_f32_16x16x32_bf16(w4f[1], h1, r, 0, 0, 0);

    float4 pv = ld4(prow + q * 4);
    float4* po = reinterpret_cast<float4*>(out + ((size_t)b * N + node) * D + q * 4);
    *po = float4{pv.x + r[0], pv.y + r[1], pv.z + r[2], pv.w + r[3]};
}

// ---------- fallback path (fp32, correctness backstop) ----------

__global__ __launch_bounds__(256, 2) void edge_atomic_kernel(
    const float* __restrict__ particles,
    const int*   __restrict__ senders,
    const int*   __restrict__ receivers,
    const float* __restrict__ W1, const float* __restrict__ b1,
    const float* __restrict__ W2, const float* __restrict__ b2,
    float* __restrict__ rel)
{
    const int idx = blockIdx.x * 256 + threadIdx.x;
    const int b = idx >> 18;
    const int e = idx & (E - 1);
    const int s = senders[e];
    const int r = receivers[e];

    float4 ein4[8];
    {
        const float4* ps = reinterpret_cast<const float4*>(particles + ((size_t)b * N + s) * D);
        const float4* pr = reinterpret_cast<const float4*>(particles + ((size_t)b * N + r) * D);
        #pragma unroll
        for (int qq = 0; qq < 4; ++qq) ein4[qq] = ps[qq];
        #pragma unroll
        for (int qq = 0; qq < 4; ++qq) ein4[4 + qq] = pr[qq];
    }
    float4 rf4[8];
    #pragma unroll
    for (int qq = 0; qq < 8; ++qq) rf4[qq] = ld4(b2 + 4 * qq);

    for (int j4 = 0; j4 < H / 4; ++j4) {
        float4 h = ld4(b1 + 4 * j4);
        const float* w1c = W1 + 4 * j4;
        #pragma unroll
        for (int kv = 0; kv < 8; ++kv) {
            const float4 ev = ein4[kv];
            h = fma4(ev.x, ld4(w1c + (4 * kv + 0) * H), h);
            h = fma4(ev.y, ld4(w1c + (4 * kv + 1) * H), h);
            h = fma4(ev.z, ld4(w1c + (4 * kv + 2) * H), h);
            h = fma4(ev.w, ld4(w1c + (4 * kv + 3) * H), h);
        }
        h = relu4(h);
        const float* w2r = W2 + (4 * j4) * R;
        #pragma unroll
        for (int qq = 0; qq < 4; ++qq) {
            const float hq = (qq == 0) ? h.x : (qq == 1) ? h.y : (qq == 2) ? h.z : h.w;
            #pragma unroll
            for (int r4 = 0; r4 < 8; ++r4)
                rf4[r4] = fma4(hq, ld4(w2r + qq * R + 4 * r4), rf4[r4]);
        }
    }
    float* dst = rel + ((size_t)b * N + r) * R;
    #pragma unroll
    for (int r4 = 0; r4 < 8; ++r4) {
        float4 v = relu4(rf4[r4]);
        atomicAdd(dst + 4 * r4 + 0, v.x);
        atomicAdd(dst + 4 * r4 + 1, v.y);
        atomicAdd(dst + 4 * r4 + 2, v.z);
        atomicAdd(dst + 4 * r4 + 3, v.w);
    }
}

__global__ __launch_bounds__(256, 2) void node_valu_kernel(
    const float* __restrict__ particles,
    const float* __restrict__ rel,
    const float* __restrict__ W3, const float* __restrict__ b3,
    const float* __restrict__ W4, const float* __restrict__ b4,
    float* __restrict__ out)
{
    const int idx = blockIdx.x * 256 + threadIdx.x;
    float4 in4[12];
    {
        const float4* pp = reinterpret_cast<const float4*>(particles + (size_t)idx * D);
        #pragma unroll
        for (int qq = 0; qq < 4; ++qq) in4[qq] = pp[qq];
        const float4* pr = reinterpret_cast<const float4*>(rel + (size_t)idx * R);
        #pragma unroll
        for (int qq = 0; qq < 8; ++qq) in4[4 + qq] = pr[qq];
    }
    float4 dl4[4];
    #pragma unroll
    for (int qq = 0; qq < 4; ++qq) dl4[qq] = ld4(b4 + 4 * qq);

    for (int j4 = 0; j4 < H / 4; ++j4) {
        float4 h = ld4(b3 + 4 * j4);
        const float* w3c = W3 + 4 * j4;
        #pragma unroll
        for (int kv = 0; kv < 12; ++kv) {
            const float4 ev = in4[kv];
            h = fma4(ev.x, ld4(w3c + (4 * kv + 0) * H), h);
            h = fma4(ev.y, ld4(w3c + (4 * kv + 1) * H), h);
            h = fma4(ev.z, ld4(w3c + (4 * kv + 2) * H), h);
            h = fma4(ev.w, ld4(w3c + (4 * kv + 3) * H), h);
        }
        h = relu4(h);
        const float* w4r = W4 + (4 * j4) * D;
        #pragma unroll
        for (int qq = 0; qq < 4; ++qq) {
            const float hq = (qq == 0) ? h.x : (qq == 1) ? h.y : (qq == 2) ? h.z : h.w;
            #pragma unroll
            for (int d4 = 0; d4 < 4; ++d4)
                dl4[d4] = fma4(hq, ld4(w4r + qq * D + 4 * d4), dl4[d4]);
        }
    }
    float4* po = reinterpret_cast<float4*>(out + (size_t)idx * D);
    #pragma unroll
    for (int qq = 0; qq < 4; ++qq) {
        float4 v = dl4[qq];
        float4 pv = in4[qq];
        po[qq] = float4{pv.x + v.x, pv.y + v.y, pv.z + v.z, pv.w + v.w};
    }
}

}  // namespace

extern "C" void kernel_launch(void* const* d_in, const int* in_sizes, int n_in,
                              void* d_out, int out_size, void* d_ws, size_t ws_size,
                              hipStream_t stream) {
    const float* particles = (const float*)d_in[0];
    const int*   senders   = (const int*)d_in[1];
    const int*   receivers = (const int*)d_in[2];
    const float* W1 = (const float*)d_in[3];
    const float* b1 = (const float*)d_in[4];
    const float* W2 = (const float*)d_in[5];
    const float* b2 = (const float*)d_in[6];
    const float* W3 = (const float*)d_in[7];
    const float* b3 = (const float*)d_in[8];
    const float* W4 = (const float*)d_in[9];
    const float* b4 = (const float*)d_in[10];
    float* out = (float*)d_out;

    // workspace layout (256-B aligned slices)
    char* ws = (char*)d_ws;
    size_t off = 0;
    auto take = [&](size_t bytes) -> char* {
        char* p = ws + off;
        off = (off + bytes + 255) & ~(size_t)255;
        return p;
    };
    int*   cnt     = (int*)  take((size_t)N * 4);
    int*   pos     = (int*)  take((size_t)N * 4);
    int2*  sr      = (int2*) take((size_t)E * 8);
    float* rel     = (float*)take((size_t)B * N * R * 4);
    short* w1p     = (short*)take((size_t)4 * 64 * 8 * 2);
    short* w2p     = (short*)take((size_t)4 * 64 * 8 * 2);
    short* w3p     = (short*)take((size_t)8 * 64 * 8 * 2);
    short* w4p     = (short*)take((size_t)2 * 64 * 8 * 2);
    const bool fast = (off <= ws_size);

    if (fast) {
        // capture-time (one-shot) occupancy check for the cooperative launch
        static int s_grid = -2;
        if (s_grid == -2) {
            int nb = 0;
            if (hipOccupancyMaxActiveBlocksPerMultiprocessor(&nb, fused_kernel, 256, 0)
                != hipSuccess) nb = 0;
            int cus = 0;
            hipDeviceProp_t prop;
            int dev = 0;
            if (hipGetDevice(&dev) == hipSuccess &&
                hipGetDeviceProperties(&prop, dev) == hipSuccess)
                cus = prop.multiProcessorCount;
            long cap = (long)nb * (long)cus;
            if (cap > 1024) cap = 1024;
            s_grid = (cap >= 64) ? (int)cap : 0;
        }

        bool done = false;
        if (s_grid >= 64) {
            Params prm;
            prm.particles = particles;
            prm.senders   = senders;
            prm.receivers = receivers;
            prm.W1 = W1; prm.b1 = b1;
            prm.W2 = W2; prm.b2 = b2;
            prm.W3 = W3; prm.b3 = b3;
            prm.W4 = W4; prm.b4 = b4;
            prm.cnt = cnt; prm.pos = pos; prm.sr = sr; prm.rel = rel;
            prm.w1p = w1p; prm.w2p = w2p; prm.w3p = w3p; prm.w4p = w4p;
            prm.out = out;
            void* args[] = { &prm };
            done = (hipLaunchCooperativeKernel(fused_kernel, dim3(s_grid), dim3(256),
                                               args, 0, stream) == hipSuccess);
        }
        if (!done) {
            // proven multi-dispatch path
            hipMemsetAsync(cnt, 0, (size_t)N * 4, stream);
            hist_prepack_kernel<<<1153, 256, 0, stream>>>(
                receivers, cnt, W1, W2, W3, W4, w1p, w2p, w3p, w4p, (float4*)rel);
            scan_kernel<<<1, 1024, 0, stream>>>(cnt, pos);
            scatter_kernel<<<E / 256, 256, 0, stream>>>(senders, receivers, pos, sr);
            edge_mfma_kernel<<<(B * E) / 256, 256, 0, stream>>>(
                particles, sr, w1p, b1, w2p, b2, rel);
            node_mfma_kernel<<<(B * N / 16) / 4, 256, 0, stream>>>(
                particles, rel, w3p, b3, w4p, b4, out);
        }
    } else {
        float* rel0 = (float*)d_ws;
        hipMemsetAsync(rel0, 0, (size_t)B * N * R * 4, stream);
        edge_atomic_kernel<<<(B * E) / 256, 256, 0, stream>>>(
            particles, senders, receivers, W1, b1, W2, b2, rel0);
        node_valu_kernel<<<(B * N) / 256, 256, 0, stream>>>(
            particles, rel0, W3, b3, W4, b4, out);
    }
}

// Round 3
// 207.489 us; speedup vs baseline: 3.1240x; 3.1240x over previous
//
#include <hip/hip_runtime.h>
#include <hip/hip_bf16.h>

namespace {

constexpr int B = 4;
constexpr int N = 8192;     // 2^13
constexpr int D = 16;
constexpr int R = 32;
constexpr int H = 64;
constexpr int E = 262144;   // 2^18

typedef __attribute__((ext_vector_type(8))) short short8;   // 8 x bf16 (4 VGPRs)
typedef __attribute__((ext_vector_type(4))) short short4v;  // 4 x bf16 (2 VGPRs)
typedef __attribute__((ext_vector_type(4))) float f32x4;    // MFMA accumulator

__device__ __forceinline__ float4 ld4(const float* p) {
    return *reinterpret_cast<const float4*>(p);
}
__device__ __forceinline__ float4 fma4(float a, float4 w, float4 c) {
    return float4{fmaf(a, w.x, c.x), fmaf(a, w.y, c.y),
                  fmaf(a, w.z, c.z), fmaf(a, w.w, c.w)};
}
__device__ __forceinline__ float4 relu4(float4 v) {
    return float4{fmaxf(v.x, 0.f), fmaxf(v.y, 0.f), fmaxf(v.z, 0.f), fmaxf(v.w, 0.f)};
}
__device__ __forceinline__ short bf16s(float f) {
    __hip_bfloat16 h = __float2bfloat16(f);   // RNE
    return __builtin_bit_cast(short, h);
}
__device__ __forceinline__ short8 pack8(float4 a, float4 b) {
    short8 o;
    o[0] = bf16s(a.x); o[1] = bf16s(a.y); o[2] = bf16s(a.z); o[3] = bf16s(a.w);
    o[4] = bf16s(b.x); o[5] = bf16s(b.y); o[6] = bf16s(b.z); o[7] = bf16s(b.w);
    return o;
}
// relu + pack 4 accumulator floats into 4 bf16 (one ds_write_b64)
__device__ __forceinline__ short4v pack4_relu(f32x4 c) {
    short4v o;
    o[0] = bf16s(fmaxf(c[0], 0.f)); o[1] = bf16s(fmaxf(c[1], 0.f));
    o[2] = bf16s(fmaxf(c[2], 0.f)); o[3] = bf16s(fmaxf(c[3], 0.f));
    return o;
}
// extract position i (0..31) from 4x int4 of packed bf16 (i must be compile-time)
__device__ __forceinline__ float red_get(const int4* uu, int i) {
    const int wsel = i >> 1;
    const int4 v = uu[wsel >> 2];
    const int word = (wsel & 3) == 0 ? v.x : (wsel & 3) == 1 ? v.y
                   : (wsel & 3) == 2 ? v.z : v.w;
    return (i & 1) ? __builtin_bit_cast(float, word & 0xffff0000)
                   : __builtin_bit_cast(float, (unsigned)word << 16);
}

constexpr int RED_S = 264;   // red stride in shorts; %8==0 keeps b128 reads 16B-aligned

__device__ __forceinline__ void prepack_w12(
    int t, const float* __restrict__ W1, const float* __restrict__ W2,
    short* __restrict__ w1p, short* __restrict__ w2p)
{
    // A/B-frag mapping (mfma_f32_16x16x32_bf16, verified m89):
    //   m|n = lane&15, k = (lane>>4)*8 + j  (identical for A and B)
    for (int i = t; i < 4 * 64 * 8; i += 256) {
        int j = i & 7, lane = (i >> 3) & 63, ct = i >> 9;
        int k = (lane >> 4) * 8 + j, n = ct * 16 + (lane & 15);
        w1p[i] = bf16s(W1[k * H + n]);
    }
    for (int i = t; i < 4 * 64 * 8; i += 256) {
        int j = i & 7, lane = (i >> 3) & 63, idx = i >> 9;
        int ct = idx >> 1, kc = idx & 1;
        int k = kc * 32 + (lane >> 4) * 8 + j, f = ct * 16 + (lane & 15);
        w2p[i] = bf16s(W2[k * R + f]);
    }
}
__device__ __forceinline__ void prepack_w34(
    int t, const float* __restrict__ W3, const float* __restrict__ W4,
    short* __restrict__ w3p, short* __restrict__ w4p)
{
    for (int i = t; i < 8 * 64 * 8; i += 256) {
        int j = i & 7, lane = (i >> 3) & 63, idx = i >> 9;
        int ct = idx >> 1, kc = idx & 1;
        int k = kc * 32 + (lane >> 4) * 8 + j, n = ct * 16 + (lane & 15);
        w3p[i] = (k < D + R) ? bf16s(W3[k * H + n]) : (short)0;
    }
    for (int i = t; i < 2 * 64 * 8; i += 256) {
        int j = i & 7, lane = (i >> 3) & 63, kc = i >> 9;
        int k = kc * 32 + (lane >> 4) * 8 + j, d = lane & 15;
        w4p[i] = bf16s(W4[k * D + d]);
    }
}

// ---------------------------------------------------------------------------
// Dispatch 2: histogram (blocks 0..1023) + last-hist-block inline scan,
//             weight prepack (block 1024), rel zero (blocks 1025..1152).
// The scan is done by whichever hist block increments `done` last: all other
// blocks' cnt atomics are complete (each block's __syncthreads drains vmcnt
// before tid0's done-increment), so exactly one block safely runs the scan.
// ---------------------------------------------------------------------------
__global__ __launch_bounds__(256) void histscan_prepack_kernel(
    const int* __restrict__ receivers, int* __restrict__ cnt,
    int* __restrict__ done, int* __restrict__ pos,
    const float* __restrict__ W1, const float* __restrict__ W2,
    const float* __restrict__ W3, const float* __restrict__ W4,
    short* __restrict__ w1p, short* __restrict__ w2p,
    short* __restrict__ w3p, short* __restrict__ w4p,
    float4* __restrict__ relz)
{
    const int tid = threadIdx.x;

    if (blockIdx.x >= 1024) {
        if (blockIdx.x == 1024) {
            prepack_w12(tid, W1, W2, w1p, w2p);
            prepack_w34(tid, W3, W4, w3p, w4p);
        } else {
            const int base = (blockIdx.x - 1025) * 256 + tid;
            #pragma unroll
            for (int i = 0; i < 8; ++i)
                relz[base + i * 32768] = float4{0.f, 0.f, 0.f, 0.f};
        }
        return;
    }

    // --- histogram ---
    atomicAdd(cnt + receivers[blockIdx.x * 256 + tid], 1);
    __syncthreads();   // waits vmcnt(0): this block's cnt atomics are acked

    __shared__ int amlast;
    if (tid == 0) {
        const int old = atomicAdd(done, 1);   // device-scope
        amlast = (old == 1023) ? 1 : 0;
    }
    __syncthreads();
    if (!amlast) return;

    // --- I am the last hist block: all cnt updates are globally visible. ---
    // Exclusive scan of 8192 counts, 32 per thread. Agent-scope atomic loads
    // guarantee we read the coherent values (cross-XCD safety).
    int c[32];
    int s = 0;
    const int cb = tid * 32;
    #pragma unroll
    for (int i = 0; i < 32; ++i) {
        c[i] = __hip_atomic_load(cnt + cb + i, __ATOMIC_RELAXED,
                                 __HIP_MEMORY_SCOPE_AGENT);
        s += c[i];
    }
    const int lane = tid & 63;
    const int wv   = tid >> 6;
    int incl = s;
    #pragma unroll
    for (int d = 1; d < 64; d <<= 1) {
        int v = __shfl_up(incl, d, 64);
        if (lane >= d) incl += v;
    }
    __shared__ int wtot[4];
    if (lane == 63) wtot[wv] = incl;
    __syncthreads();
    int base = incl - s;
    #pragma unroll
    for (int i = 0; i < 4; ++i) base += (i < wv) ? wtot[i] : 0;
    #pragma unroll
    for (int i = 0; i < 32; ++i) {
        pos[cb + i] = base;
        base += c[i];
    }
}

// ---------------------------------------------------------------------------
// Dispatch 3: scatter edges into receiver-sorted order.
// ---------------------------------------------------------------------------
__global__ __launch_bounds__(256) void scatter_kernel(
    const int* __restrict__ senders, const int* __restrict__ receivers,
    int* __restrict__ pos, int2* __restrict__ sr)
{
    int e = blockIdx.x * 256 + threadIdx.x;
    if (e < E) {
        int r = receivers[e];
        int p = atomicAdd(pos + r, 1);
        sr[p] = int2{senders[e], r};
    }
}

// ---------------------------------------------------------------------------
// Dispatch 4: batch-fused MFMA edge MLP + segmented reduction.
// 1024 blocks; each owns 256 sorted positions and processes ALL 4 batches,
// amortizing sr load / shfl distribution / bmask / weight fragments 4x and
// prefetching batch b+1's gathers under batch b's MFMA+reduce.
// (Logic identical to round-2's correctness-verified fused P4.)
// ---------------------------------------------------------------------------
__global__ __launch_bounds__(256, 4) void edge_mfma4_kernel(
    const float* __restrict__ particles,
    const int2*  __restrict__ sr,
    const short* __restrict__ w1p, const float* __restrict__ b1,
    const short* __restrict__ w2p, const float* __restrict__ b2,
    float* __restrict__ rel)
{
    __shared__ short red[R * RED_S];          // [f][pos] bf16, stride 264 (16.9 KB)
    __shared__ short hbuf[4][16 * 72];        // per-wave [edge][hidden], stride 72
    __shared__ int   rs[256];

    const int tid  = threadIdx.x;
    const int lane = tid & 63;
    const int w    = tid >> 6;
    const int p0   = blockIdx.x * 256;
    const int l15  = lane & 15;
    const int q    = lane >> 4;

    const int2 srv = sr[p0 + tid];
    rs[tid] = srv.y;

    // weight fragments + biases (batch-invariant, loaded once)
    short8 w1f[4], w2f[4];
    #pragma unroll
    for (int mt = 0; mt < 4; ++mt)
        w1f[mt] = *reinterpret_cast<const short8*>(w1p + (mt * 64 + lane) * 8);
    #pragma unroll
    for (int i = 0; i < 4; ++i)
        w2f[i] = *reinterpret_cast<const short8*>(w2p + (i * 64 + lane) * 8);
    f32x4 bias1[4];
    #pragma unroll
    for (int mt = 0; mt < 4; ++mt) {
        float4 t4 = ld4(b1 + mt * 16 + q * 4);
        bias1[mt] = f32x4{t4.x, t4.y, t4.z, t4.w};
    }
    const float bias2a = b2[l15];
    const float bias2b = b2[16 + l15];

    // row offsets (batch-invariant): distribute via shfl once
    int off[4];
    #pragma unroll
    for (int t = 0; t < 4; ++t) {
        const int srow = __shfl(srv.x, t * 16 + l15);
        const int rrow = __shfl(srv.y, t * 16 + l15);
        off[t] = ((q < 2) ? srow : rrow) * D + (q & 1) * 8;
    }
    __syncthreads();                 // rs visible block-wide

    // segment-boundary mask for this (group, feature) -- batch-invariant
    const int g2 = tid >> 5;
    const int f  = tid & 31;
    const int gb = g2 * 32;
    unsigned bmask = 0;
    int first;
    {
        int4 r4[8];
        #pragma unroll
        for (int i = 0; i < 8; ++i)
            r4[i] = *reinterpret_cast<const int4*>(rs + gb + 4 * i);
        first = r4[0].x;
        int prev = first;
        #pragma unroll
        for (int i = 1; i < 32; ++i) {
            const int4 v4 = r4[i >> 2];
            const int rr = (i & 3) == 0 ? v4.x : (i & 3) == 1 ? v4.y
                         : (i & 3) == 2 ? v4.z : v4.w;
            if (rr != prev) bmask |= (1u << i);
            prev = rr;
        }
    }

    // gather batch 0
    float4 g0[4], g1[4];
    #pragma unroll
    for (int t = 0; t < 4; ++t) {
        const float* s0 = particles + off[t];
        g0[t] = ld4(s0);
        g1[t] = ld4(s0 + 4);
    }

    short* hb = &hbuf[w][0];

    #pragma unroll 1
    for (int b = 0; b < 4; ++b) {
        short8 af[4];
        #pragma unroll
        for (int t = 0; t < 4; ++t) af[t] = pack8(g0[t], g1[t]);
        if (b < 3) {   // prefetch next batch under this batch's compute
            const float* nb = particles + (size_t)(b + 1) * N * D;
            #pragma unroll
            for (int t = 0; t < 4; ++t) {
                g0[t] = ld4(nb + off[t]);
                g1[t] = ld4(nb + off[t] + 4);
            }
        }

        #pragma unroll
        for (int t = 0; t < 4; ++t) {
            // layer1: 4 hidden m-tiles, K=32; XOR-swizzled tile slot
            #pragma unroll
            for (int mt = 0; mt < 4; ++mt) {
                f32x4 cc = bias1[mt];
                cc = __builtin_amdgcn_mfma_f32_16x16x32_bf16(w1f[mt], af[t], cc, 0, 0, 0);
                const int smt = (mt + l15) & 3;
                *reinterpret_cast<short4v*>(hb + l15 * 72 + smt * 16 + q * 4) = pack4_relu(cc);
            }
            const int sm0 = ((q >> 1) + l15) & 3;
            const int sm1 = (2 + (q >> 1) + l15) & 3;
            short8 h0 = *reinterpret_cast<const short8*>(hb + l15 * 72 + sm0 * 16 + (q & 1) * 8);
            short8 h1 = *reinterpret_cast<const short8*>(hb + l15 * 72 + sm1 * 16 + (q & 1) * 8);

            // layer2: D2[edge][f], 2 f-tiles, K=64
            f32x4 r0 = {bias2a, bias2a, bias2a, bias2a};
            f32x4 r1 = {bias2b, bias2b, bias2b, bias2b};
            r0 = __builtin_amdgcn_mfma_f32_16x16x32_bf16(h0, w2f[0], r0, 0, 0, 0);
            r0 = __builtin_amdgcn_mfma_f32_16x16x32_bf16(h1, w2f[1], r0, 0, 0, 0);
            r1 = __builtin_amdgcn_mfma_f32_16x16x32_bf16(h0, w2f[2], r1, 0, 0, 0);
            r1 = __builtin_amdgcn_mfma_f32_16x16x32_bf16(h1, w2f[3], r1, 0, 0, 0);

            const int pb2 = w * 64 + t * 16 + q * 4;
            *reinterpret_cast<short4v*>(red + l15 * RED_S + pb2)        = pack4_relu(r0);
            *reinterpret_cast<short4v*>(red + (16 + l15) * RED_S + pb2) = pack4_relu(r1);
        }
        __syncthreads();

        // segmented reduction for batch b (boundary mask precomputed)
        int4 uu[4];
        #pragma unroll
        for (int i = 0; i < 4; ++i)
            uu[i] = *reinterpret_cast<const int4*>(red + f * RED_S + gb + 8 * i);
        float* relb = rel + (size_t)b * N * R;
        if (bmask == 0) {
            float acc = 0.f;
            #pragma unroll
            for (int i = 0; i < 32; ++i) acc += red_get(uu, i);
            atomicAdd(relb + (size_t)first * R + f, acc);
        } else {
            float acc = 0.f;
            int cur = first;
            #pragma unroll
            for (int i = 0; i < 32; ++i) {
                if (bmask & (1u << i)) {
                    atomicAdd(relb + (size_t)cur * R + f, acc);
                    acc = 0.f;
                    cur = rs[gb + i];
                }
                acc += red_get(uu, i);
            }
            atomicAdd(relb + (size_t)cur * R + f, acc);
        }
        if (b < 3) __syncthreads();   // red reused next batch
    }
}

// ---------------------------------------------------------------------------
// Dispatch 5: MFMA node MLP, one 16-node tile per wave.
// ---------------------------------------------------------------------------
__global__ __launch_bounds__(256, 4) void node_mfma_kernel(
    const float* __restrict__ particles,
    const float* __restrict__ rel,
    const short* __restrict__ w3p, const float* __restrict__ b3,
    const short* __restrict__ w4p, const float* __restrict__ b4,
    float* __restrict__ out)
{
    __shared__ short hbuf[4][16 * 72];

    const int tid  = threadIdx.x;
    const int lane = tid & 63;
    const int w    = tid >> 6;
    const int tile = blockIdx.x * 4 + w;        // [0, B*N/16)
    const int b    = tile >> 9;                 // 512 tiles per batch
    const int l15  = lane & 15;
    const int q    = lane >> 4;
    const int node = (tile & 511) * 16 + l15;

    const float* prow = particles + ((size_t)b * N + node) * D;
    const float* rrow = rel + ((size_t)b * N + node) * R;

    const float* src0 = (q < 2) ? (prow + (q & 1) * 8) : (rrow + (q & 1) * 8);
    float4 c0a = ld4(src0), c0b = ld4(src0 + 4);
    float4 c1a = {0.f, 0.f, 0.f, 0.f}, c1b = {0.f, 0.f, 0.f, 0.f};
    if (q < 2) { c1a = ld4(rrow + 16 + q * 8); c1b = ld4(rrow + 20 + q * 8); }

    short8 w3f[8], w4f[2];
    #pragma unroll
    for (int i = 0; i < 8; ++i)
        w3f[i] = *reinterpret_cast<const short8*>(w3p + (i * 64 + lane) * 8);
    #pragma unroll
    for (int i = 0; i < 2; ++i)
        w4f[i] = *reinterpret_cast<const short8*>(w4p + (i * 64 + lane) * 8);

    f32x4 bias3[4];
    #pragma unroll
    for (int mt = 0; mt < 4; ++mt) {
        float4 t4 = ld4(b3 + mt * 16 + q * 4);
        bias3[mt] = f32x4{t4.x, t4.y, t4.z, t4.w};
    }
    f32x4 bias4;
    { float4 t4 = ld4(b4 + q * 4); bias4 = f32x4{t4.x, t4.y, t4.z, t4.w}; }

    short8 a0 = pack8(c0a, c0b);
    short8 a1 = pack8(c1a, c1b);

    short* hb = &hbuf[w][0];
    #pragma unroll
    for (int mt = 0; mt < 4; ++mt) {
        f32x4 c = bias3[mt];
        c = __builtin_amdgcn_mfma_f32_16x16x32_bf16(w3f[mt * 2 + 0], a0, c, 0, 0, 0);
        c = __builtin_amdgcn_mfma_f32_16x16x32_bf16(w3f[mt * 2 + 1], a1, c, 0, 0, 0);
        *reinterpret_cast<short4v*>(hb + l15 * 72 + mt * 16 + q * 4) = pack4_relu(c);
    }
    short8 h0 = *reinterpret_cast<const short8*>(hb + l15 * 72 + q * 8);
    short8 h1 = *reinterpret_cast<const short8*>(hb + l15 * 72 + 32 + q * 8);

    f32x4 r = bias4;
    r = __builtin_amdgcn_mfma_f32_16x16x32_bf16(w4f[0], h0, r, 0, 0, 0);
    r = __builtin_amdgcn_mfma_f32_16x16x32_bf16(w4f[1], h1, r, 0, 0, 0);

    float4 pv = ld4(prow + q * 4);
    float4* po = reinterpret_cast<float4*>(out + ((size_t)b * N + node) * D + q * 4);
    *po = float4{pv.x + r[0], pv.y + r[1], pv.z + r[2], pv.w + r[3]};
}

// ---------- fallback path (fp32, correctness backstop) ----------

__global__ __launch_bounds__(256, 2) void edge_atomic_kernel(
    const float* __restrict__ particles,
    const int*   __restrict__ senders,
    const int*   __restrict__ receivers,
    const float* __restrict__ W1, const float* __restrict__ b1,
    const float* __restrict__ W2, const float* __restrict__ b2,
    float* __restrict__ rel)
{
    const int idx = blockIdx.x * 256 + threadIdx.x;
    const int b = idx >> 18;
    const int e = idx & (E - 1);
    const int s = senders[e];
    const int r = receivers[e];

    float4 ein4[8];
    {
        const float4* ps = reinterpret_cast<const float4*>(particles + ((size_t)b * N + s) * D);
        const float4* pr = reinterpret_cast<const float4*>(particles + ((size_t)b * N + r) * D);
        #pragma unroll
        for (int qq = 0; qq < 4; ++qq) ein4[qq] = ps[qq];
        #pragma unroll
        for (int qq = 0; qq < 4; ++qq) ein4[4 + qq] = pr[qq];
    }
    float4 rf4[8];
    #pragma unroll
    for (int qq = 0; qq < 8; ++qq) rf4[qq] = ld4(b2 + 4 * qq);

    for (int j4 = 0; j4 < H / 4; ++j4) {
        float4 h = ld4(b1 + 4 * j4);
        const float* w1c = W1 + 4 * j4;
        #pragma unroll
        for (int kv = 0; kv < 8; ++kv) {
            const float4 ev = ein4[kv];
            h = fma4(ev.x, ld4(w1c + (4 * kv + 0) * H), h);
            h = fma4(ev.y, ld4(w1c + (4 * kv + 1) * H), h);
            h = fma4(ev.z, ld4(w1c + (4 * kv + 2) * H), h);
            h = fma4(ev.w, ld4(w1c + (4 * kv + 3) * H), h);
        }
        h = relu4(h);
        const float* w2r = W2 + (4 * j4) * R;
        #pragma unroll
        for (int qq = 0; qq < 4; ++qq) {
            const float hq = (qq == 0) ? h.x : (qq == 1) ? h.y : (qq == 2) ? h.z : h.w;
            #pragma unroll
            for (int r4 = 0; r4 < 8; ++r4)
                rf4[r4] = fma4(hq, ld4(w2r + qq * R + 4 * r4), rf4[r4]);
        }
    }
    float* dst = rel + ((size_t)b * N + r) * R;
    #pragma unroll
    for (int r4 = 0; r4 < 8; ++r4) {
        float4 v = relu4(rf4[r4]);
        atomicAdd(dst + 4 * r4 + 0, v.x);
        atomicAdd(dst + 4 * r4 + 1, v.y);
        atomicAdd(dst + 4 * r4 + 2, v.z);
        atomicAdd(dst + 4 * r4 + 3, v.w);
    }
}

__global__ __launch_bounds__(256, 2) void node_valu_kernel(
    const float* __restrict__ particles,
    const float* __restrict__ rel,
    const float* __restrict__ W3, const float* __restrict__ b3,
    const float* __restrict__ W4, const float* __restrict__ b4,
    float* __restrict__ out)
{
    const int idx = blockIdx.x * 256 + threadIdx.x;
    float4 in4[12];
    {
        const float4* pp = reinterpret_cast<const float4*>(particles + (size_t)idx * D);
        #pragma unroll
        for (int qq = 0; qq < 4; ++qq) in4[qq] = pp[qq];
        const float4* pr = reinterpret_cast<const float4*>(rel + (size_t)idx * R);
        #pragma unroll
        for (int qq = 0; qq < 8; ++qq) in4[4 + qq] = pr[qq];
    }
    float4 dl4[4];
    #pragma unroll
    for (int qq = 0; qq < 4; ++qq) dl4[qq] = ld4(b4 + 4 * qq);

    for (int j4 = 0; j4 < H / 4; ++j4) {
        float4 h = ld4(b3 + 4 * j4);
        const float* w3c = W3 + 4 * j4;
        #pragma unroll
        for (int kv = 0; kv < 12; ++kv) {
            const float4 ev = in4[kv];
            h = fma4(ev.x, ld4(w3c + (4 * kv + 0) * H), h);
            h = fma4(ev.y, ld4(w3c + (4 * kv + 1) * H), h);
            h = fma4(ev.z, ld4(w3c + (4 * kv + 2) * H), h);
            h = fma4(ev.w, ld4(w3c + (4 * kv + 3) * H), h);
        }
        h = relu4(h);
        const float* w4r = W4 + (4 * j4) * D;
        #pragma unroll
        for (int qq = 0; qq < 4; ++qq) {
            const float hq = (qq == 0) ? h.x : (qq == 1) ? h.y : (qq == 2) ? h.z : h.w;
            #pragma unroll
            for (int d4 = 0; d4 < 4; ++d4)
                dl4[d4] = fma4(hq, ld4(w4r + qq * D + 4 * d4), dl4[d4]);
        }
    }
    float4* po = reinterpret_cast<float4*>(out + (size_t)idx * D);
    #pragma unroll
    for (int qq = 0; qq < 4; ++qq) {
        float4 v = dl4[qq];
        float4 pv = in4[qq];
        po[qq] = float4{pv.x + v.x, pv.y + v.y, pv.z + v.z, pv.w + v.w};
    }
}

}  // namespace

extern "C" void kernel_launch(void* const* d_in, const int* in_sizes, int n_in,
                              void* d_out, int out_size, void* d_ws, size_t ws_size,
                              hipStream_t stream) {
    const float* particles = (const float*)d_in[0];
    const int*   senders   = (const int*)d_in[1];
    const int*   receivers = (const int*)d_in[2];
    const float* W1 = (const float*)d_in[3];
    const float* b1 = (const float*)d_in[4];
    const float* W2 = (const float*)d_in[5];
    const float* b2 = (const float*)d_in[6];
    const float* W3 = (const float*)d_in[7];
    const float* b3 = (const float*)d_in[8];
    const float* W4 = (const float*)d_in[9];
    const float* b4 = (const float*)d_in[10];
    float* out = (float*)d_out;

    // workspace layout (256-B aligned slices)
    char* ws = (char*)d_ws;
    size_t off = 0;
    auto take = [&](size_t bytes) -> char* {
        char* p = ws + off;
        off = (off + bytes + 255) & ~(size_t)255;
        return p;
    };
    int*   cnt     = (int*)  take((size_t)N * 4);
    int*   done    = (int*)  take(4);            // contiguous after cnt
    int*   pos     = (int*)  take((size_t)N * 4);
    int2*  sr      = (int2*) take((size_t)E * 8);
    float* rel     = (float*)take((size_t)B * N * R * 4);
    short* w1p     = (short*)take((size_t)4 * 64 * 8 * 2);
    short* w2p     = (short*)take((size_t)4 * 64 * 8 * 2);
    short* w3p     = (short*)take((size_t)8 * 64 * 8 * 2);
    short* w4p     = (short*)take((size_t)2 * 64 * 8 * 2);
    const bool fast = (off <= ws_size);

    if (fast) {
        // one memset covers cnt (N*4 bytes) + done (4 bytes right after)
        hipMemsetAsync(cnt, 0, (size_t)N * 4 + 4, stream);
        histscan_prepack_kernel<<<1153, 256, 0, stream>>>(
            receivers, cnt, done, pos,
            W1, W2, W3, W4, w1p, w2p, w3p, w4p, (float4*)rel);
        scatter_kernel<<<E / 256, 256, 0, stream>>>(senders, receivers, pos, sr);
        edge_mfma4_kernel<<<E / 256, 256, 0, stream>>>(
            particles, sr, w1p, b1, w2p, b2, rel);
        node_mfma_kernel<<<(B * N / 16) / 4, 256, 0, stream>>>(
            particles, rel, w3p, b3, w4p, b4, out);
    } else {
        float* rel0 = (float*)d_ws;
        hipMemsetAsync(rel0, 0, (size_t)B * N * R * 4, stream);
        edge_atomic_kernel<<<(B * E) / 256, 256, 0, stream>>>(
            particles, senders, receivers, W1, b1, W2, b2, rel0);
        node_valu_kernel<<<(B * N) / 256, 256, 0, stream>>>(
            particles, rel0, W3, b3, W4, b4, out);
    }
}

// Round 4
// 157.065 us; speedup vs baseline: 4.1270x; 1.3210x over previous
//
#include <hip/hip_runtime.h>
#include <hip/hip_bf16.h>

namespace {

constexpr int B = 4;
constexpr int N = 8192;     // 2^13
constexpr int D = 16;
constexpr int R = 32;
constexpr int H = 64;
constexpr int E = 262144;   // 2^18

typedef __attribute__((ext_vector_type(8))) short short8;   // 8 x bf16 (4 VGPRs)
typedef __attribute__((ext_vector_type(4))) short short4v;  // 4 x bf16 (2 VGPRs)
typedef __attribute__((ext_vector_type(4))) float f32x4;    // MFMA accumulator

__device__ __forceinline__ float4 ld4(const float* p) {
    return *reinterpret_cast<const float4*>(p);
}
__device__ __forceinline__ float4 fma4(float a, float4 w, float4 c) {
    return float4{fmaf(a, w.x, c.x), fmaf(a, w.y, c.y),
                  fmaf(a, w.z, c.z), fmaf(a, w.w, c.w)};
}
__device__ __forceinline__ float4 relu4(float4 v) {
    return float4{fmaxf(v.x, 0.f), fmaxf(v.y, 0.f), fmaxf(v.z, 0.f), fmaxf(v.w, 0.f)};
}
__device__ __forceinline__ short bf16s(float f) {
    __hip_bfloat16 h = __float2bfloat16(f);   // RNE
    return __builtin_bit_cast(short, h);
}
__device__ __forceinline__ short8 pack8(float4 a, float4 b) {
    short8 o;
    o[0] = bf16s(a.x); o[1] = bf16s(a.y); o[2] = bf16s(a.z); o[3] = bf16s(a.w);
    o[4] = bf16s(b.x); o[5] = bf16s(b.y); o[6] = bf16s(b.z); o[7] = bf16s(b.w);
    return o;
}
// relu + pack 4 accumulator floats into 4 bf16 (one ds_write_b64)
__device__ __forceinline__ short4v pack4_relu(f32x4 c) {
    short4v o;
    o[0] = bf16s(fmaxf(c[0], 0.f)); o[1] = bf16s(fmaxf(c[1], 0.f));
    o[2] = bf16s(fmaxf(c[2], 0.f)); o[3] = bf16s(fmaxf(c[3], 0.f));
    return o;
}
// extract position i (0..31) from 4x int4 of packed bf16 (i must be compile-time)
__device__ __forceinline__ float red_get(const int4* uu, int i) {
    const int wsel = i >> 1;
    const int4 v = uu[wsel >> 2];
    const int word = (wsel & 3) == 0 ? v.x : (wsel & 3) == 1 ? v.y
                   : (wsel & 3) == 2 ? v.z : v.w;
    return (i & 1) ? __builtin_bit_cast(float, word & 0xffff0000)
                   : __builtin_bit_cast(float, (unsigned)word << 16);
}

constexpr int RED_S = 264;   // red stride in shorts; %8==0 keeps b128 reads 16B-aligned

__device__ __forceinline__ void prepack_w12(
    int t, const float* __restrict__ W1, const float* __restrict__ W2,
    short* __restrict__ w1p, short* __restrict__ w2p)
{
    // A/B-frag mapping (mfma_f32_16x16x32_bf16, verified m89):
    //   m|n = lane&15, k = (lane>>4)*8 + j  (identical for A and B)
    for (int i = t; i < 4 * 64 * 8; i += 256) {
        int j = i & 7, lane = (i >> 3) & 63, ct = i >> 9;
        int k = (lane >> 4) * 8 + j, n = ct * 16 + (lane & 15);
        w1p[i] = bf16s(W1[k * H + n]);
    }
    for (int i = t; i < 4 * 64 * 8; i += 256) {
        int j = i & 7, lane = (i >> 3) & 63, idx = i >> 9;
        int ct = idx >> 1, kc = idx & 1;
        int k = kc * 32 + (lane >> 4) * 8 + j, f = ct * 16 + (lane & 15);
        w2p[i] = bf16s(W2[k * R + f]);
    }
}
__device__ __forceinline__ void prepack_w34(
    int t, const float* __restrict__ W3, const float* __restrict__ W4,
    short* __restrict__ w3p, short* __restrict__ w4p)
{
    for (int i = t; i < 8 * 64 * 8; i += 256) {
        int j = i & 7, lane = (i >> 3) & 63, idx = i >> 9;
        int ct = idx >> 1, kc = idx & 1;
        int k = kc * 32 + (lane >> 4) * 8 + j, n = ct * 16 + (lane & 15);
        w3p[i] = (k < D + R) ? bf16s(W3[k * H + n]) : (short)0;
    }
    for (int i = t; i < 2 * 64 * 8; i += 256) {
        int j = i & 7, lane = (i >> 3) & 63, kc = i >> 9;
        int k = kc * 32 + (lane >> 4) * 8 + j, d = lane & 15;
        w4p[i] = bf16s(W4[k * D + d]);
    }
}

// ---------------------------------------------------------------------------
// Dispatch 2: histogram (blocks 0..1023) + last-hist-block inline scan,
//             weight prepack (block 1024), rel zero (blocks 1025..1152).
// ---------------------------------------------------------------------------
__global__ __launch_bounds__(256) void histscan_prepack_kernel(
    const int* __restrict__ receivers, int* __restrict__ cnt,
    int* __restrict__ done, int* __restrict__ pos,
    const float* __restrict__ W1, const float* __restrict__ W2,
    const float* __restrict__ W3, const float* __restrict__ W4,
    short* __restrict__ w1p, short* __restrict__ w2p,
    short* __restrict__ w3p, short* __restrict__ w4p,
    float4* __restrict__ relz)
{
    const int tid = threadIdx.x;

    if (blockIdx.x >= 1024) {
        if (blockIdx.x == 1024) {
            prepack_w12(tid, W1, W2, w1p, w2p);
            prepack_w34(tid, W3, W4, w3p, w4p);
        } else {
            const int base = (blockIdx.x - 1025) * 256 + tid;
            #pragma unroll
            for (int i = 0; i < 8; ++i)
                relz[base + i * 32768] = float4{0.f, 0.f, 0.f, 0.f};
        }
        return;
    }

    // --- histogram ---
    atomicAdd(cnt + receivers[blockIdx.x * 256 + tid], 1);
    __syncthreads();   // waits vmcnt(0): this block's cnt atomics are acked

    __shared__ int amlast;
    if (tid == 0) {
        const int old = atomicAdd(done, 1);   // device-scope
        amlast = (old == 1023) ? 1 : 0;
    }
    __syncthreads();
    if (!amlast) return;

    // --- last hist block: all cnt updates globally visible; do the scan ---
    int c[32];
    int s = 0;
    const int cb = tid * 32;
    #pragma unroll
    for (int i = 0; i < 32; ++i) {
        c[i] = __hip_atomic_load(cnt + cb + i, __ATOMIC_RELAXED,
                                 __HIP_MEMORY_SCOPE_AGENT);
        s += c[i];
    }
    const int lane = tid & 63;
    const int wv   = tid >> 6;
    int incl = s;
    #pragma unroll
    for (int d = 1; d < 64; d <<= 1) {
        int v = __shfl_up(incl, d, 64);
        if (lane >= d) incl += v;
    }
    __shared__ int wtot[4];
    if (lane == 63) wtot[wv] = incl;
    __syncthreads();
    int base = incl - s;
    #pragma unroll
    for (int i = 0; i < 4; ++i) base += (i < wv) ? wtot[i] : 0;
    #pragma unroll
    for (int i = 0; i < 32; ++i) {
        pos[cb + i] = base;
        base += c[i];
    }
}

// ---------------------------------------------------------------------------
// Dispatch 3: scatter edges into receiver-sorted order.
// ---------------------------------------------------------------------------
__global__ __launch_bounds__(256) void scatter_kernel(
    const int* __restrict__ senders, const int* __restrict__ receivers,
    int* __restrict__ pos, int2* __restrict__ sr)
{
    int e = blockIdx.x * 256 + threadIdx.x;
    if (e < E) {
        int r = receivers[e];
        int p = atomicAdd(pos + r, 1);
        sr[p] = int2{senders[e], r};
    }
}

// ---------------------------------------------------------------------------
// Dispatch 4: MFMA edge MLP + two-stage segmented reduction (4096 blocks,
// one batch-window each — the proven overlap-friendly structure).
//
// Reduction: edges are receiver-sorted, so only the window's FIRST and LAST
// receivers can straddle a block boundary -> atomicAdd. Every interior
// receiver's sum is complete within this block -> plain store into the
// pre-zeroed rel (receiver rows are 128B-exclusive, no false sharing).
//   stage 1 (per 32-pos group x feature): first segment -> pre[], last ->
//     suf[], strictly-interior segments (complete receivers) -> plain store.
//   stage 2 (32 threads, one per feature): merge suffix->prefix chains
//     across the 8 groups; flush #0 and the final flush atomically, middle
//     flushes as plain stores.
// Cuts rel atomics ~2.1M -> ~0.26M (64B-line RMW traffic 128MB -> ~20MB).
// ---------------------------------------------------------------------------
__global__ __launch_bounds__(256, 4) void edge_mfma_kernel(
    const float* __restrict__ particles,
    const int2*  __restrict__ sr,
    const short* __restrict__ w1p, const float* __restrict__ b1,
    const short* __restrict__ w2p, const float* __restrict__ b2,
    float* __restrict__ rel)
{
    __shared__ short red[R * RED_S];          // [f][pos] bf16, stride 264 (16.9 KB)
    __shared__ short hbuf[4][16 * 72];        // per-wave [edge][hidden], stride 72
    __shared__ int   rs[256];
    __shared__ float pre[8][33];              // first-segment sum per (group,feat)
    __shared__ float suf[8][33];              // last-segment sum per (group,feat)
    __shared__ int   kcnt[8];                 // segments per group

    const int tid  = threadIdx.x;
    const int lane = tid & 63;
    const int w    = tid >> 6;
    const int b    = blockIdx.x >> 10;        // 1024 blocks per batch
    const int p0   = (blockIdx.x & 1023) * 256;
    const int l15  = lane & 15;
    const int q    = lane >> 4;

    const int2 srv = sr[p0 + tid];
    rs[tid] = srv.y;

    // hoisted gather: distribute rows via shfl, issue all 8 dwordx4 loads up front
    float4 a0[4], a1[4];
    #pragma unroll
    for (int t = 0; t < 4; ++t) {
        int srow = __shfl(srv.x, t * 16 + l15);
        int rrow = __shfl(srv.y, t * 16 + l15);
        int row = (q < 2) ? srow : rrow;
        const float* src = particles + ((size_t)b * N + row) * D + (q & 1) * 8;
        a0[t] = ld4(src);
        a1[t] = ld4(src + 4);
    }

    // weight fragments (L2-hot, coalesced)
    short8 w1f[4], w2f[4];
    #pragma unroll
    for (int mt = 0; mt < 4; ++mt)
        w1f[mt] = *reinterpret_cast<const short8*>(w1p + (mt * 64 + lane) * 8);
    #pragma unroll
    for (int i = 0; i < 4; ++i)
        w2f[i] = *reinterpret_cast<const short8*>(w2p + (i * 64 + lane) * 8);

    f32x4 bias1[4];
    #pragma unroll
    for (int mt = 0; mt < 4; ++mt) {
        float4 t4 = ld4(b1 + mt * 16 + q * 4);
        bias1[mt] = f32x4{t4.x, t4.y, t4.z, t4.w};
    }
    const float bias2a = b2[l15];
    const float bias2b = b2[16 + l15];

    short8 af[4];
    #pragma unroll
    for (int t = 0; t < 4; ++t) af[t] = pack8(a0[t], a1[t]);

    short* hb = &hbuf[w][0];

    #pragma unroll
    for (int t = 0; t < 4; ++t) {
        // layer1: 4 hidden m-tiles, K=32; XOR-swizzled tile slot (R9-verified)
        #pragma unroll
        for (int mt = 0; mt < 4; ++mt) {
            f32x4 c = bias1[mt];
            c = __builtin_amdgcn_mfma_f32_16x16x32_bf16(w1f[mt], af[t], c, 0, 0, 0);
            const int smt = (mt + l15) & 3;
            *reinterpret_cast<short4v*>(hb + l15 * 72 + smt * 16 + q * 4) = pack4_relu(c);
        }
        const int sm0 = ((q >> 1) + l15) & 3;
        const int sm1 = (2 + (q >> 1) + l15) & 3;
        short8 h0 = *reinterpret_cast<const short8*>(hb + l15 * 72 + sm0 * 16 + (q & 1) * 8);
        short8 h1 = *reinterpret_cast<const short8*>(hb + l15 * 72 + sm1 * 16 + (q & 1) * 8);

        // layer2: D2[edge][f], 2 f-tiles, K=64
        f32x4 r0 = {bias2a, bias2a, bias2a, bias2a};
        f32x4 r1 = {bias2b, bias2b, bias2b, bias2b};
        r0 = __builtin_amdgcn_mfma_f32_16x16x32_bf16(h0, w2f[0], r0, 0, 0, 0);
        r0 = __builtin_amdgcn_mfma_f32_16x16x32_bf16(h1, w2f[1], r0, 0, 0, 0);
        r1 = __builtin_amdgcn_mfma_f32_16x16x32_bf16(h0, w2f[2], r1, 0, 0, 0);
        r1 = __builtin_amdgcn_mfma_f32_16x16x32_bf16(h1, w2f[3], r1, 0, 0, 0);

        const int pb2 = w * 64 + t * 16 + q * 4;
        *reinterpret_cast<short4v*>(red + l15 * RED_S + pb2)        = pack4_relu(r0);
        *reinterpret_cast<short4v*>(red + (16 + l15) * RED_S + pb2) = pack4_relu(r1);
    }
    __syncthreads();

    // ---- stage 1: per-(group,feature) segmented partial sums ----
    const int g2 = tid >> 5;
    const int f  = tid & 31;
    const int gb = g2 * 32;
    float* relb = rel + (size_t)b * N * R;

    unsigned bmask = 0;
    int first;
    {
        int4 r4[8];
        #pragma unroll
        for (int i = 0; i < 8; ++i)
            r4[i] = *reinterpret_cast<const int4*>(rs + gb + 4 * i);
        first = r4[0].x;
        int prev = first;
        #pragma unroll
        for (int i = 1; i < 32; ++i) {
            const int4 v4 = r4[i >> 2];
            const int rr = (i & 3) == 0 ? v4.x : (i & 3) == 1 ? v4.y
                         : (i & 3) == 2 ? v4.z : v4.w;
            if (rr != prev) bmask |= (1u << i);
            prev = rr;
        }
    }
    if (f == 0) kcnt[g2] = __popc(bmask) + 1;

    int4 uu[4];
    #pragma unroll
    for (int i = 0; i < 4; ++i)
        uu[i] = *reinterpret_cast<const int4*>(red + f * RED_S + gb + 8 * i);

    {
        float acc = 0.f;
        int cur = first;
        int seg = 0;
        #pragma unroll
        for (int i = 0; i < 32; ++i) {
            if (bmask & (1u << i)) {
                if (seg == 0) pre[g2][f] = acc;
                else relb[(size_t)cur * R + f] = acc;   // interior complete receiver
                ++seg;
                acc = 0.f;
                cur = rs[gb + i];
            }
            acc += red_get(uu, i);
        }
        suf[g2][f] = acc;   // last segment (k==1: whole group; pre unwritten)
    }
    __syncthreads();

    // ---- stage 2: merge chains across groups (one thread per feature) ----
    if (tid < 32) {
        int   cur2 = rs[0];
        float a2   = 0.f;
        int   nfl  = 0;
        #pragma unroll
        for (int g = 0; g < 8; ++g) {
            const int   rf   = rs[g * 32];
            const int   rl   = rs[g * 32 + 31];
            const int   kk   = kcnt[g];
            const float sufv = suf[g][tid];
            if (kk == 1) {
                if (rf == cur2) a2 += sufv;
                else {
                    if (nfl == 0) atomicAdd(relb + (size_t)cur2 * R + tid, a2);
                    else          relb[(size_t)cur2 * R + tid] = a2;
                    ++nfl;
                    cur2 = rf; a2 = sufv;
                }
            } else {
                const float prev = pre[g][tid];
                if (rf == cur2) {
                    a2 += prev;
                    if (nfl == 0) atomicAdd(relb + (size_t)cur2 * R + tid, a2);
                    else          relb[(size_t)cur2 * R + tid] = a2;
                    ++nfl;
                } else {
                    if (nfl == 0) atomicAdd(relb + (size_t)cur2 * R + tid, a2);
                    else          relb[(size_t)cur2 * R + tid] = a2;
                    ++nfl;
                    relb[(size_t)rf * R + tid] = prev;   // complete (starts at group edge, ends inside g)
                    ++nfl;
                }
                cur2 = rl; a2 = sufv;
            }
        }
        atomicAdd(relb + (size_t)cur2 * R + tid, a2);   // may span into next window
    }
}

// ---------------------------------------------------------------------------
// Dispatch 5: MFMA node MLP, one 16-node tile per wave.
// ---------------------------------------------------------------------------
__global__ __launch_bounds__(256, 4) void node_mfma_kernel(
    const float* __restrict__ particles,
    const float* __restrict__ rel,
    const short* __restrict__ w3p, const float* __restrict__ b3,
    const short* __restrict__ w4p, const float* __restrict__ b4,
    float* __restrict__ out)
{
    __shared__ short hbuf[4][16 * 72];

    const int tid  = threadIdx.x;
    const int lane = tid & 63;
    const int w    = tid >> 6;
    const int tile = blockIdx.x * 4 + w;        // [0, B*N/16)
    const int b    = tile >> 9;                 // 512 tiles per batch
    const int l15  = lane & 15;
    const int q    = lane >> 4;
    const int node = (tile & 511) * 16 + l15;

    const float* prow = particles + ((size_t)b * N + node) * D;
    const float* rrow = rel + ((size_t)b * N + node) * R;

    const float* src0 = (q < 2) ? (prow + (q & 1) * 8) : (rrow + (q & 1) * 8);
    float4 c0a = ld4(src0), c0b = ld4(src0 + 4);
    float4 c1a = {0.f, 0.f, 0.f, 0.f}, c1b = {0.f, 0.f, 0.f, 0.f};
    if (q < 2) { c1a = ld4(rrow + 16 + q * 8); c1b = ld4(rrow + 20 + q * 8); }

    short8 w3f[8], w4f[2];
    #pragma unroll
    for (int i = 0; i < 8; ++i)
        w3f[i] = *reinterpret_cast<const short8*>(w3p + (i * 64 + lane) * 8);
    #pragma unroll
    for (int i = 0; i < 2; ++i)
        w4f[i] = *reinterpret_cast<const short8*>(w4p + (i * 64 + lane) * 8);

    f32x4 bias3[4];
    #pragma unroll
    for (int mt = 0; mt < 4; ++mt) {
        float4 t4 = ld4(b3 + mt * 16 + q * 4);
        bias3[mt] = f32x4{t4.x, t4.y, t4.z, t4.w};
    }
    f32x4 bias4;
    { float4 t4 = ld4(b4 + q * 4); bias4 = f32x4{t4.x, t4.y, t4.z, t4.w}; }

    short8 a0 = pack8(c0a, c0b);
    short8 a1 = pack8(c1a, c1b);

    short* hb = &hbuf[w][0];
    #pragma unroll
    for (int mt = 0; mt < 4; ++mt) {
        f32x4 c = bias3[mt];
        c = __builtin_amdgcn_mfma_f32_16x16x32_bf16(w3f[mt * 2 + 0], a0, c, 0, 0, 0);
        c = __builtin_amdgcn_mfma_f32_16x16x32_bf16(w3f[mt * 2 + 1], a1, c, 0, 0, 0);
        *reinterpret_cast<short4v*>(hb + l15 * 72 + mt * 16 + q * 4) = pack4_relu(c);
    }
    short8 h0 = *reinterpret_cast<const short8*>(hb + l15 * 72 + q * 8);
    short8 h1 = *reinterpret_cast<const short8*>(hb + l15 * 72 + 32 + q * 8);

    f32x4 r = bias4;
    r = __builtin_amdgcn_mfma_f32_16x16x32_bf16(w4f[0], h0, r, 0, 0, 0);
    r = __builtin_amdgcn_mfma_f32_16x16x32_bf16(w4f[1], h1, r, 0, 0, 0);

    float4 pv = ld4(prow + q * 4);
    float4* po = reinterpret_cast<float4*>(out + ((size_t)b * N + node) * D + q * 4);
    *po = float4{pv.x + r[0], pv.y + r[1], pv.z + r[2], pv.w + r[3]};
}

// ---------- fallback path (fp32, correctness backstop) ----------

__global__ __launch_bounds__(256, 2) void edge_atomic_kernel(
    const float* __restrict__ particles,
    const int*   __restrict__ senders,
    const int*   __restrict__ receivers,
    const float* __restrict__ W1, const float* __restrict__ b1,
    const float* __restrict__ W2, const float* __restrict__ b2,
    float* __restrict__ rel)
{
    const int idx = blockIdx.x * 256 + threadIdx.x;
    const int b = idx >> 18;
    const int e = idx & (E - 1);
    const int s = senders[e];
    const int r = receivers[e];

    float4 ein4[8];
    {
        const float4* ps = reinterpret_cast<const float4*>(particles + ((size_t)b * N + s) * D);
        const float4* pr = reinterpret_cast<const float4*>(particles + ((size_t)b * N + r) * D);
        #pragma unroll
        for (int qq = 0; qq < 4; ++qq) ein4[qq] = ps[qq];
        #pragma unroll
        for (int qq = 0; qq < 4; ++qq) ein4[4 + qq] = pr[qq];
    }
    float4 rf4[8];
    #pragma unroll
    for (int qq = 0; qq < 8; ++qq) rf4[qq] = ld4(b2 + 4 * qq);

    for (int j4 = 0; j4 < H / 4; ++j4) {
        float4 h = ld4(b1 + 4 * j4);
        const float* w1c = W1 + 4 * j4;
        #pragma unroll
        for (int kv = 0; kv < 8; ++kv) {
            const float4 ev = ein4[kv];
            h = fma4(ev.x, ld4(w1c + (4 * kv + 0) * H), h);
            h = fma4(ev.y, ld4(w1c + (4 * kv + 1) * H), h);
            h = fma4(ev.z, ld4(w1c + (4 * kv + 2) * H), h);
            h = fma4(ev.w, ld4(w1c + (4 * kv + 3) * H), h);
        }
        h = relu4(h);
        const float* w2r = W2 + (4 * j4) * R;
        #pragma unroll
        for (int qq = 0; qq < 4; ++qq) {
            const float hq = (qq == 0) ? h.x : (qq == 1) ? h.y : (qq == 2) ? h.z : h.w;
            #pragma unroll
            for (int r4 = 0; r4 < 8; ++r4)
                rf4[r4] = fma4(hq, ld4(w2r + qq * R + 4 * r4), rf4[r4]);
        }
    }
    float* dst = rel + ((size_t)b * N + r) * R;
    #pragma unroll
    for (int r4 = 0; r4 < 8; ++r4) {
        float4 v = relu4(rf4[r4]);
        atomicAdd(dst + 4 * r4 + 0, v.x);
        atomicAdd(dst + 4 * r4 + 1, v.y);
        atomicAdd(dst + 4 * r4 + 2, v.z);
        atomicAdd(dst + 4 * r4 + 3, v.w);
    }
}

__global__ __launch_bounds__(256, 2) void node_valu_kernel(
    const float* __restrict__ particles,
    const float* __restrict__ rel,
    const float* __restrict__ W3, const float* __restrict__ b3,
    const float* __restrict__ W4, const float* __restrict__ b4,
    float* __restrict__ out)
{
    const int idx = blockIdx.x * 256 + threadIdx.x;
    float4 in4[12];
    {
        const float4* pp = reinterpret_cast<const float4*>(particles + (size_t)idx * D);
        #pragma unroll
        for (int qq = 0; qq < 4; ++qq) in4[qq] = pp[qq];
        const float4* pr = reinterpret_cast<const float4*>(rel + (size_t)idx * R);
        #pragma unroll
        for (int qq = 0; qq < 8; ++qq) in4[4 + qq] = pr[qq];
    }
    float4 dl4[4];
    #pragma unroll
    for (int qq = 0; qq < 4; ++qq) dl4[qq] = ld4(b4 + 4 * qq);

    for (int j4 = 0; j4 < H / 4; ++j4) {
        float4 h = ld4(b3 + 4 * j4);
        const float* w3c = W3 + 4 * j4;
        #pragma unroll
        for (int kv = 0; kv < 12; ++kv) {
            const float4 ev = in4[kv];
            h = fma4(ev.x, ld4(w3c + (4 * kv + 0) * H), h);
            h = fma4(ev.y, ld4(w3c + (4 * kv + 1) * H), h);
            h = fma4(ev.z, ld4(w3c + (4 * kv + 2) * H), h);
            h = fma4(ev.w, ld4(w3c + (4 * kv + 3) * H), h);
        }
        h = relu4(h);
        const float* w4r = W4 + (4 * j4) * D;
        #pragma unroll
        for (int qq = 0; qq < 4; ++qq) {
            const float hq = (qq == 0) ? h.x : (qq == 1) ? h.y : (qq == 2) ? h.z : h.w;
            #pragma unroll
            for (int d4 = 0; d4 < 4; ++d4)
                dl4[d4] = fma4(hq, ld4(w4r + qq * D + 4 * d4), dl4[d4]);
        }
    }
    float4* po = reinterpret_cast<float4*>(out + (size_t)idx * D);
    #pragma unroll
    for (int qq = 0; qq < 4; ++qq) {
        float4 v = dl4[qq];
        float4 pv = in4[qq];
        po[qq] = float4{pv.x + v.x, pv.y + v.y, pv.z + v.z, pv.w + v.w};
    }
}

}  // namespace

extern "C" void kernel_launch(void* const* d_in, const int* in_sizes, int n_in,
                              void* d_out, int out_size, void* d_ws, size_t ws_size,
                              hipStream_t stream) {
    const float* particles = (const float*)d_in[0];
    const int*   senders   = (const int*)d_in[1];
    const int*   receivers = (const int*)d_in[2];
    const float* W1 = (const float*)d_in[3];
    const float* b1 = (const float*)d_in[4];
    const float* W2 = (const float*)d_in[5];
    const float* b2 = (const float*)d_in[6];
    const float* W3 = (const float*)d_in[7];
    const float* b3 = (const float*)d_in[8];
    const float* W4 = (const float*)d_in[9];
    const float* b4 = (const float*)d_in[10];
    float* out = (float*)d_out;

    // workspace layout (256-B aligned slices)
    char* ws = (char*)d_ws;
    size_t off = 0;
    auto take = [&](size_t bytes) -> char* {
        char* p = ws + off;
        off = (off + bytes + 255) & ~(size_t)255;
        return p;
    };
    int*   cnt     = (int*)  take((size_t)N * 4);
    int*   done    = (int*)  take(4);            // contiguous after cnt
    int*   pos     = (int*)  take((size_t)N * 4);
    int2*  sr      = (int2*) take((size_t)E * 8);
    float* rel     = (float*)take((size_t)B * N * R * 4);
    short* w1p     = (short*)take((size_t)4 * 64 * 8 * 2);
    short* w2p     = (short*)take((size_t)4 * 64 * 8 * 2);
    short* w3p     = (short*)take((size_t)8 * 64 * 8 * 2);
    short* w4p     = (short*)take((size_t)2 * 64 * 8 * 2);
    const bool fast = (off <= ws_size);

    if (fast) {
        // one memset covers cnt (N*4 bytes) + done (4 bytes right after)
        hipMemsetAsync(cnt, 0, (size_t)N * 4 + 4, stream);
        histscan_prepack_kernel<<<1153, 256, 0, stream>>>(
            receivers, cnt, done, pos,
            W1, W2, W3, W4, w1p, w2p, w3p, w4p, (float4*)rel);
        scatter_kernel<<<E / 256, 256, 0, stream>>>(senders, receivers, pos, sr);
        edge_mfma_kernel<<<(B * E) / 256, 256, 0, stream>>>(
            particles, sr, w1p, b1, w2p, b2, rel);
        node_mfma_kernel<<<(B * N / 16) / 4, 256, 0, stream>>>(
            particles, rel, w3p, b3, w4p, b4, out);
    } else {
        float* rel0 = (float*)d_ws;
        hipMemsetAsync(rel0, 0, (size_t)B * N * R * 4, stream);
        edge_atomic_kernel<<<(B * E) / 256, 256, 0, stream>>>(
            particles, senders, receivers, W1, b1, W2, b2, rel0);
        node_valu_kernel<<<(B * N) / 256, 256, 0, stream>>>(
            particles, rel0, W3, b3, W4, b4, out);
    }
}

// Round 5
// 155.844 us; speedup vs baseline: 4.1593x; 1.0078x over previous
//
#include <hip/hip_runtime.h>
#include <hip/hip_bf16.h>

namespace {

constexpr int B = 4;
constexpr int N = 8192;     // 2^13
constexpr int D = 16;
constexpr int R = 32;
constexpr int H = 64;
constexpr int E = 262144;   // 2^18

typedef __attribute__((ext_vector_type(8))) short short8;   // 8 x bf16 (4 VGPRs)
typedef __attribute__((ext_vector_type(4))) short short4v;  // 4 x bf16 (2 VGPRs)
typedef __attribute__((ext_vector_type(4))) float f32x4;    // MFMA accumulator

__device__ __forceinline__ float4 ld4(const float* p) {
    return *reinterpret_cast<const float4*>(p);
}
__device__ __forceinline__ float4 fma4(float a, float4 w, float4 c) {
    return float4{fmaf(a, w.x, c.x), fmaf(a, w.y, c.y),
                  fmaf(a, w.z, c.z), fmaf(a, w.w, c.w)};
}
__device__ __forceinline__ float4 relu4(float4 v) {
    return float4{fmaxf(v.x, 0.f), fmaxf(v.y, 0.f), fmaxf(v.z, 0.f), fmaxf(v.w, 0.f)};
}
__device__ __forceinline__ short bf16s(float f) {
    __hip_bfloat16 h = __float2bfloat16(f);   // RNE
    return __builtin_bit_cast(short, h);
}
__device__ __forceinline__ short8 pack8(float4 a, float4 b) {
    short8 o;
    o[0] = bf16s(a.x); o[1] = bf16s(a.y); o[2] = bf16s(a.z); o[3] = bf16s(a.w);
    o[4] = bf16s(b.x); o[5] = bf16s(b.y); o[6] = bf16s(b.z); o[7] = bf16s(b.w);
    return o;
}
// relu + pack 4 accumulator floats into 4 bf16
__device__ __forceinline__ short4v pack4_relu(f32x4 c) {
    short4v o;
    o[0] = bf16s(fmaxf(c[0], 0.f)); o[1] = bf16s(fmaxf(c[1], 0.f));
    o[2] = bf16s(fmaxf(c[2], 0.f)); o[3] = bf16s(fmaxf(c[3], 0.f));
    return o;
}
// concat two packed short4v into an MFMA A/B fragment (pure register op)
__device__ __forceinline__ short8 cat44(short4v a, short4v b) {
    int2 ia = __builtin_bit_cast(int2, a);
    int2 ib = __builtin_bit_cast(int2, b);
    int4 v{ia.x, ia.y, ib.x, ib.y};
    return __builtin_bit_cast(short8, v);
}
// extract position i (0..31) from 4x int4 of packed bf16 (i must be compile-time)
__device__ __forceinline__ float red_get(const int4* uu, int i) {
    const int wsel = i >> 1;
    const int4 v = uu[wsel >> 2];
    const int word = (wsel & 3) == 0 ? v.x : (wsel & 3) == 1 ? v.y
                   : (wsel & 3) == 2 ? v.z : v.w;
    return (i & 1) ? __builtin_bit_cast(float, word & 0xffff0000)
                   : __builtin_bit_cast(float, (unsigned)word << 16);
}

constexpr int RED_S = 264;   // red stride in shorts; %8==0 keeps b128 reads 16B-aligned

// hidden-permutation for layer-2/4 row packing: the C/D accumulator of layer 1/3
// (lane q*16+l15, tile mt, reg rg = hidden mt*16+q*4+rg) is consumed DIRECTLY as
// the next layer's A/B fragment (k = q*8+j) iff row k is sourced from hidden
//   rho(k) = 32*(k>>5) + ((k>>2)&1)*16 + ((k>>3)&3)*4 + (k&3)
// (bijection on each 32-chunk). Then h0 = concat(tile0,tile1), h1 = concat(tile2,tile3)
// with NO LDS transpose. Output is invariant because W1/b1 (resp. W3/b3) keep the
// standard packing C(mt,q,rg) = mt*16+q*4+rg and rho maps frag slots onto it 1:1.

__device__ __forceinline__ void prepack_w12(
    int t, const float* __restrict__ W1, const float* __restrict__ W2,
    short* __restrict__ w1p, short* __restrict__ w2p)
{
    // A/B-frag mapping (mfma_f32_16x16x32_bf16, verified m89):
    //   m|n = lane&15, k = (lane>>4)*8 + j  (identical for A and B)
    for (int i = t; i < 4 * 64 * 8; i += 256) {
        int j = i & 7, lane = (i >> 3) & 63, ct = i >> 9;
        int k = (lane >> 4) * 8 + j, n = ct * 16 + (lane & 15);
        w1p[i] = bf16s(W1[k * H + n]);
    }
    for (int i = t; i < 4 * 64 * 8; i += 256) {
        int j = i & 7, lane = (i >> 3) & 63, idx = i >> 9;
        int ct = idx >> 1, kc = idx & 1;
        // rho-remapped row (see above): was kc*32 + (lane>>4)*8 + j
        int k = kc * 32 + (j >> 2) * 16 + ((lane >> 4) & 3) * 4 + (j & 3);
        int f = ct * 16 + (lane & 15);
        w2p[i] = bf16s(W2[k * R + f]);
    }
}
__device__ __forceinline__ void prepack_w34(
    int t, const float* __restrict__ W3, const float* __restrict__ W4,
    short* __restrict__ w3p, short* __restrict__ w4p)
{
    for (int i = t; i < 8 * 64 * 8; i += 256) {
        int j = i & 7, lane = (i >> 3) & 63, idx = i >> 9;
        int ct = idx >> 1, kc = idx & 1;
        int k = kc * 32 + (lane >> 4) * 8 + j, n = ct * 16 + (lane & 15);
        w3p[i] = (k < D + R) ? bf16s(W3[k * H + n]) : (short)0;
    }
    for (int i = t; i < 2 * 64 * 8; i += 256) {
        int j = i & 7, lane = (i >> 3) & 63, kc = i >> 9;
        // rho-remapped row: was kc*32 + (lane>>4)*8 + j
        int k = kc * 32 + (j >> 2) * 16 + ((lane >> 4) & 3) * 4 + (j & 3);
        int d = lane & 15;
        w4p[i] = bf16s(W4[k * D + d]);
    }
}

// ---------------------------------------------------------------------------
// Dispatch 2: histogram (blocks 0..1023) + last-hist-block inline scan,
//             weight prepack (block 1024), rel zero (blocks 1025..1152).
// ---------------------------------------------------------------------------
__global__ __launch_bounds__(256) void histscan_prepack_kernel(
    const int* __restrict__ receivers, int* __restrict__ cnt,
    int* __restrict__ done, int* __restrict__ pos,
    const float* __restrict__ W1, const float* __restrict__ W2,
    const float* __restrict__ W3, const float* __restrict__ W4,
    short* __restrict__ w1p, short* __restrict__ w2p,
    short* __restrict__ w3p, short* __restrict__ w4p,
    float4* __restrict__ relz)
{
    const int tid = threadIdx.x;

    if (blockIdx.x >= 1024) {
        if (blockIdx.x == 1024) {
            prepack_w12(tid, W1, W2, w1p, w2p);
            prepack_w34(tid, W3, W4, w3p, w4p);
        } else {
            const int base = (blockIdx.x - 1025) * 256 + tid;
            #pragma unroll
            for (int i = 0; i < 8; ++i)
                relz[base + i * 32768] = float4{0.f, 0.f, 0.f, 0.f};
        }
        return;
    }

    // --- histogram ---
    atomicAdd(cnt + receivers[blockIdx.x * 256 + tid], 1);
    __syncthreads();   // waits vmcnt(0): this block's cnt atomics are acked

    __shared__ int amlast;
    if (tid == 0) {
        const int old = atomicAdd(done, 1);   // device-scope
        amlast = (old == 1023) ? 1 : 0;
    }
    __syncthreads();
    if (!amlast) return;

    // --- last hist block: all cnt updates globally visible; do the scan ---
    int c[32];
    int s = 0;
    const int cb = tid * 32;
    #pragma unroll
    for (int i = 0; i < 32; ++i) {
        c[i] = __hip_atomic_load(cnt + cb + i, __ATOMIC_RELAXED,
                                 __HIP_MEMORY_SCOPE_AGENT);
        s += c[i];
    }
    const int lane = tid & 63;
    const int wv   = tid >> 6;
    int incl = s;
    #pragma unroll
    for (int d = 1; d < 64; d <<= 1) {
        int v = __shfl_up(incl, d, 64);
        if (lane >= d) incl += v;
    }
    __shared__ int wtot[4];
    if (lane == 63) wtot[wv] = incl;
    __syncthreads();
    int base = incl - s;
    #pragma unroll
    for (int i = 0; i < 4; ++i) base += (i < wv) ? wtot[i] : 0;
    #pragma unroll
    for (int i = 0; i < 32; ++i) {
        pos[cb + i] = base;
        base += c[i];
    }
}

// ---------------------------------------------------------------------------
// Dispatch 3: scatter edges into receiver-sorted order.
// ---------------------------------------------------------------------------
__global__ __launch_bounds__(256) void scatter_kernel(
    const int* __restrict__ senders, const int* __restrict__ receivers,
    int* __restrict__ pos, int2* __restrict__ sr)
{
    int e = blockIdx.x * 256 + threadIdx.x;
    if (e < E) {
        int r = receivers[e];
        int p = atomicAdd(pos + r, 1);
        sr[p] = int2{senders[e], r};
    }
}

// ---------------------------------------------------------------------------
// Dispatch 4: MFMA edge MLP + two-stage segmented reduction (4096 blocks).
// L1->L2 transpose eliminated via rho-remapped W2 rows: h-frags are the lane's
// own packed accumulators (no hbuf LDS). LDS ~20 KB -> up to 8 blocks/CU.
// ---------------------------------------------------------------------------
__global__ __launch_bounds__(256, 4) void edge_mfma_kernel(
    const float* __restrict__ particles,
    const int2*  __restrict__ sr,
    const short* __restrict__ w1p, const float* __restrict__ b1,
    const short* __restrict__ w2p, const float* __restrict__ b2,
    float* __restrict__ rel)
{
    __shared__ short red[R * RED_S];          // [f][pos] bf16, stride 264 (16.9 KB)
    __shared__ int   rs[256];
    __shared__ float pre[8][33];              // first-segment sum per (group,feat)
    __shared__ float suf[8][33];              // last-segment sum per (group,feat)
    __shared__ int   kcnt[8];                 // segments per group

    const int tid  = threadIdx.x;
    const int lane = tid & 63;
    const int w    = tid >> 6;
    const int b    = blockIdx.x >> 10;        // 1024 blocks per batch
    const int p0   = (blockIdx.x & 1023) * 256;
    const int l15  = lane & 15;
    const int q    = lane >> 4;

    const int2 srv = sr[p0 + tid];
    rs[tid] = srv.y;

    // hoisted gather: distribute rows via shfl, issue all 8 dwordx4 loads up front
    float4 a0[4], a1[4];
    #pragma unroll
    for (int t = 0; t < 4; ++t) {
        int srow = __shfl(srv.x, t * 16 + l15);
        int rrow = __shfl(srv.y, t * 16 + l15);
        int row = (q < 2) ? srow : rrow;
        const float* src = particles + ((size_t)b * N + row) * D + (q & 1) * 8;
        a0[t] = ld4(src);
        a1[t] = ld4(src + 4);
    }

    // weight fragments (L2-hot, coalesced)
    short8 w1f[4], w2f[4];
    #pragma unroll
    for (int mt = 0; mt < 4; ++mt)
        w1f[mt] = *reinterpret_cast<const short8*>(w1p + (mt * 64 + lane) * 8);
    #pragma unroll
    for (int i = 0; i < 4; ++i)
        w2f[i] = *reinterpret_cast<const short8*>(w2p + (i * 64 + lane) * 8);

    f32x4 bias1[4];
    #pragma unroll
    for (int mt = 0; mt < 4; ++mt) {
        float4 t4 = ld4(b1 + mt * 16 + q * 4);
        bias1[mt] = f32x4{t4.x, t4.y, t4.z, t4.w};
    }
    const float bias2a = b2[l15];
    const float bias2b = b2[16 + l15];

    short8 af[4];
    #pragma unroll
    for (int t = 0; t < 4; ++t) af[t] = pack8(a0[t], a1[t]);

    #pragma unroll
    for (int t = 0; t < 4; ++t) {
        // layer1: 4 hidden m-tiles, K=32 -> packed bf16 kept in registers
        f32x4 c0 = __builtin_amdgcn_mfma_f32_16x16x32_bf16(w1f[0], af[t], bias1[0], 0, 0, 0);
        f32x4 c1 = __builtin_amdgcn_mfma_f32_16x16x32_bf16(w1f[1], af[t], bias1[1], 0, 0, 0);
        f32x4 c2 = __builtin_amdgcn_mfma_f32_16x16x32_bf16(w1f[2], af[t], bias1[2], 0, 0, 0);
        f32x4 c3 = __builtin_amdgcn_mfma_f32_16x16x32_bf16(w1f[3], af[t], bias1[3], 0, 0, 0);
        short8 h0 = cat44(pack4_relu(c0), pack4_relu(c1));   // k = 0..31 (rho rows)
        short8 h1 = cat44(pack4_relu(c2), pack4_relu(c3));   // k = 32..63

        // layer2: D2[edge][f], 2 f-tiles, K=64
        f32x4 r0 = {bias2a, bias2a, bias2a, bias2a};
        f32x4 r1 = {bias2b, bias2b, bias2b, bias2b};
        r0 = __builtin_amdgcn_mfma_f32_16x16x32_bf16(h0, w2f[0], r0, 0, 0, 0);
        r0 = __builtin_amdgcn_mfma_f32_16x16x32_bf16(h1, w2f[1], r0, 0, 0, 0);
        r1 = __builtin_amdgcn_mfma_f32_16x16x32_bf16(h0, w2f[2], r1, 0, 0, 0);
        r1 = __builtin_amdgcn_mfma_f32_16x16x32_bf16(h1, w2f[3], r1, 0, 0, 0);

        const int pb2 = w * 64 + t * 16 + q * 4;
        *reinterpret_cast<short4v*>(red + l15 * RED_S + pb2)        = pack4_relu(r0);
        *reinterpret_cast<short4v*>(red + (16 + l15) * RED_S + pb2) = pack4_relu(r1);
    }
    __syncthreads();

    // ---- stage 1: per-(group,feature) segmented partial sums ----
    const int g2 = tid >> 5;
    const int f  = tid & 31;
    const int gb = g2 * 32;
    float* relb = rel + (size_t)b * N * R;

    unsigned bmask = 0;
    int first;
    {
        int4 r4[8];
        #pragma unroll
        for (int i = 0; i < 8; ++i)
            r4[i] = *reinterpret_cast<const int4*>(rs + gb + 4 * i);
        first = r4[0].x;
        int prev = first;
        #pragma unroll
        for (int i = 1; i < 32; ++i) {
            const int4 v4 = r4[i >> 2];
            const int rr = (i & 3) == 0 ? v4.x : (i & 3) == 1 ? v4.y
                         : (i & 3) == 2 ? v4.z : v4.w;
            if (rr != prev) bmask |= (1u << i);
            prev = rr;
        }
    }
    if (f == 0) kcnt[g2] = __popc(bmask) + 1;

    int4 uu[4];
    #pragma unroll
    for (int i = 0; i < 4; ++i)
        uu[i] = *reinterpret_cast<const int4*>(red + f * RED_S + gb + 8 * i);

    {
        float acc = 0.f;
        int cur = first;
        int seg = 0;
        #pragma unroll
        for (int i = 0; i < 32; ++i) {
            if (bmask & (1u << i)) {
                if (seg == 0) pre[g2][f] = acc;
                else relb[(size_t)cur * R + f] = acc;   // interior complete receiver
                ++seg;
                acc = 0.f;
                cur = rs[gb + i];
            }
            acc += red_get(uu, i);
        }
        suf[g2][f] = acc;   // last segment (k==1: whole group; pre unwritten)
    }
    __syncthreads();

    // ---- stage 2: merge chains across groups (one thread per feature) ----
    if (tid < 32) {
        int   cur2 = rs[0];
        float a2   = 0.f;
        int   nfl  = 0;
        #pragma unroll
        for (int g = 0; g < 8; ++g) {
            const int   rf   = rs[g * 32];
            const int   rl   = rs[g * 32 + 31];
            const int   kk   = kcnt[g];
            const float sufv = suf[g][tid];
            if (kk == 1) {
                if (rf == cur2) a2 += sufv;
                else {
                    if (nfl == 0) atomicAdd(relb + (size_t)cur2 * R + tid, a2);
                    else          relb[(size_t)cur2 * R + tid] = a2;
                    ++nfl;
                    cur2 = rf; a2 = sufv;
                }
            } else {
                const float prev = pre[g][tid];
                if (rf == cur2) {
                    a2 += prev;
                    if (nfl == 0) atomicAdd(relb + (size_t)cur2 * R + tid, a2);
                    else          relb[(size_t)cur2 * R + tid] = a2;
                    ++nfl;
                } else {
                    if (nfl == 0) atomicAdd(relb + (size_t)cur2 * R + tid, a2);
                    else          relb[(size_t)cur2 * R + tid] = a2;
                    ++nfl;
                    relb[(size_t)rf * R + tid] = prev;   // complete receiver
                    ++nfl;
                }
                cur2 = rl; a2 = sufv;
            }
        }
        atomicAdd(relb + (size_t)cur2 * R + tid, a2);   // may span into next window
    }
}

// ---------------------------------------------------------------------------
// Dispatch 5: MFMA node MLP, one 16-node tile per wave. Zero LDS (rho-remap).
// ---------------------------------------------------------------------------
__global__ __launch_bounds__(256, 4) void node_mfma_kernel(
    const float* __restrict__ particles,
    const float* __restrict__ rel,
    const short* __restrict__ w3p, const float* __restrict__ b3,
    const short* __restrict__ w4p, const float* __restrict__ b4,
    float* __restrict__ out)
{
    const int tid  = threadIdx.x;
    const int lane = tid & 63;
    const int w    = tid >> 6;
    const int tile = blockIdx.x * 4 + w;        // [0, B*N/16)
    const int b    = tile >> 9;                 // 512 tiles per batch
    const int l15  = lane & 15;
    const int q    = lane >> 4;
    const int node = (tile & 511) * 16 + l15;

    const float* prow = particles + ((size_t)b * N + node) * D;
    const float* rrow = rel + ((size_t)b * N + node) * R;

    const float* src0 = (q < 2) ? (prow + (q & 1) * 8) : (rrow + (q & 1) * 8);
    float4 c0a = ld4(src0), c0b = ld4(src0 + 4);
    float4 c1a = {0.f, 0.f, 0.f, 0.f}, c1b = {0.f, 0.f, 0.f, 0.f};
    if (q < 2) { c1a = ld4(rrow + 16 + q * 8); c1b = ld4(rrow + 20 + q * 8); }

    short8 w3f[8], w4f[2];
    #pragma unroll
    for (int i = 0; i < 8; ++i)
        w3f[i] = *reinterpret_cast<const short8*>(w3p + (i * 64 + lane) * 8);
    #pragma unroll
    for (int i = 0; i < 2; ++i)
        w4f[i] = *reinterpret_cast<const short8*>(w4p + (i * 64 + lane) * 8);

    f32x4 bias3[4];
    #pragma unroll
    for (int mt = 0; mt < 4; ++mt) {
        float4 t4 = ld4(b3 + mt * 16 + q * 4);
        bias3[mt] = f32x4{t4.x, t4.y, t4.z, t4.w};
    }
    f32x4 bias4;
    { float4 t4 = ld4(b4 + q * 4); bias4 = f32x4{t4.x, t4.y, t4.z, t4.w}; }

    short8 a0 = pack8(c0a, c0b);
    short8 a1 = pack8(c1a, c1b);

    // layer3: 4 hidden m-tiles, K=48 (padded 64) -> packed in registers
    f32x4 c0 = bias3[0], c1 = bias3[1], c2 = bias3[2], c3 = bias3[3];
    c0 = __builtin_amdgcn_mfma_f32_16x16x32_bf16(w3f[0], a0, c0, 0, 0, 0);
    c0 = __builtin_amdgcn_mfma_f32_16x16x32_bf16(w3f[1], a1, c0, 0, 0, 0);
    c1 = __builtin_amdgcn_mfma_f32_16x16x32_bf16(w3f[2], a0, c1, 0, 0, 0);
    c1 = __builtin_amdgcn_mfma_f32_16x16x32_bf16(w3f[3], a1, c1, 0, 0, 0);
    c2 = __builtin_amdgcn_mfma_f32_16x16x32_bf16(w3f[4], a0, c2, 0, 0, 0);
    c2 = __builtin_amdgcn_mfma_f32_16x16x32_bf16(w3f[5], a1, c2, 0, 0, 0);
    c3 = __builtin_amdgcn_mfma_f32_16x16x32_bf16(w3f[6], a0, c3, 0, 0, 0);
    c3 = __builtin_amdgcn_mfma_f32_16x16x32_bf16(w3f[7], a1, c3, 0, 0, 0);
    short8 h0 = cat44(pack4_relu(c0), pack4_relu(c1));   // k = 0..31 (rho rows)
    short8 h1 = cat44(pack4_relu(c2), pack4_relu(c3));   // k = 32..63

    f32x4 r = bias4;
    r = __builtin_amdgcn_mfma_f32_16x16x32_bf16(w4f[0], h0, r, 0, 0, 0);
    r = __builtin_amdgcn_mfma_f32_16x16x32_bf16(w4f[1], h1, r, 0, 0, 0);

    float4 pv = ld4(prow + q * 4);
    float4* po = reinterpret_cast<float4*>(out + ((size_t)b * N + node) * D + q * 4);
    *po = float4{pv.x + r[0], pv.y + r[1], pv.z + r[2], pv.w + r[3]};
}

// ---------- fallback path (fp32, correctness backstop) ----------

__global__ __launch_bounds__(256, 2) void edge_atomic_kernel(
    const float* __restrict__ particles,
    const int*   __restrict__ senders,
    const int*   __restrict__ receivers,
    const float* __restrict__ W1, const float* __restrict__ b1,
    const float* __restrict__ W2, const float* __restrict__ b2,
    float* __restrict__ rel)
{
    const int idx = blockIdx.x * 256 + threadIdx.x;
    const int b = idx >> 18;
    const int e = idx & (E - 1);
    const int s = senders[e];
    const int r = receivers[e];

    float4 ein4[8];
    {
        const float4* ps = reinterpret_cast<const float4*>(particles + ((size_t)b * N + s) * D);
        const float4* pr = reinterpret_cast<const float4*>(particles + ((size_t)b * N + r) * D);
        #pragma unroll
        for (int qq = 0; qq < 4; ++qq) ein4[qq] = ps[qq];
        #pragma unroll
        for (int qq = 0; qq < 4; ++qq) ein4[4 + qq] = pr[qq];
    }
    float4 rf4[8];
    #pragma unroll
    for (int qq = 0; qq < 8; ++qq) rf4[qq] = ld4(b2 + 4 * qq);

    for (int j4 = 0; j4 < H / 4; ++j4) {
        float4 h = ld4(b1 + 4 * j4);
        const float* w1c = W1 + 4 * j4;
        #pragma unroll
        for (int kv = 0; kv < 8; ++kv) {
            const float4 ev = ein4[kv];
            h = fma4(ev.x, ld4(w1c + (4 * kv + 0) * H), h);
            h = fma4(ev.y, ld4(w1c + (4 * kv + 1) * H), h);
            h = fma4(ev.z, ld4(w1c + (4 * kv + 2) * H), h);
            h = fma4(ev.w, ld4(w1c + (4 * kv + 3) * H), h);
        }
        h = relu4(h);
        const float* w2r = W2 + (4 * j4) * R;
        #pragma unroll
        for (int qq = 0; qq < 4; ++qq) {
            const float hq = (qq == 0) ? h.x : (qq == 1) ? h.y : (qq == 2) ? h.z : h.w;
            #pragma unroll
            for (int r4 = 0; r4 < 8; ++r4)
                rf4[r4] = fma4(hq, ld4(w2r + qq * R + 4 * r4), rf4[r4]);
        }
    }
    float* dst = rel + ((size_t)b * N + r) * R;
    #pragma unroll
    for (int r4 = 0; r4 < 8; ++r4) {
        float4 v = relu4(rf4[r4]);
        atomicAdd(dst + 4 * r4 + 0, v.x);
        atomicAdd(dst + 4 * r4 + 1, v.y);
        atomicAdd(dst + 4 * r4 + 2, v.z);
        atomicAdd(dst + 4 * r4 + 3, v.w);
    }
}

__global__ __launch_bounds__(256, 2) void node_valu_kernel(
    const float* __restrict__ particles,
    const float* __restrict__ rel,
    const float* __restrict__ W3, const float* __restrict__ b3,
    const float* __restrict__ W4, const float* __restrict__ b4,
    float* __restrict__ out)
{
    const int idx = blockIdx.x * 256 + threadIdx.x;
    float4 in4[12];
    {
        const float4* pp = reinterpret_cast<const float4*>(particles + (size_t)idx * D);
        #pragma unroll
        for (int qq = 0; qq < 4; ++qq) in4[qq] = pp[qq];
        const float4* pr = reinterpret_cast<const float4*>(rel + (size_t)idx * R);
        #pragma unroll
        for (int qq = 0; qq < 8; ++qq) in4[4 + qq] = pr[qq];
    }
    float4 dl4[4];
    #pragma unroll
    for (int qq = 0; qq < 4; ++qq) dl4[qq] = ld4(b4 + 4 * qq);

    for (int j4 = 0; j4 < H / 4; ++j4) {
        float4 h = ld4(b3 + 4 * j4);
        const float* w3c = W3 + 4 * j4;
        #pragma unroll
        for (int kv = 0; kv < 12; ++kv) {
            const float4 ev = in4[kv];
            h = fma4(ev.x, ld4(w3c + (4 * kv + 0) * H), h);
            h = fma4(ev.y, ld4(w3c + (4 * kv + 1) * H), h);
            h = fma4(ev.z, ld4(w3c + (4 * kv + 2) * H), h);
            h = fma4(ev.w, ld4(w3c + (4 * kv + 3) * H), h);
        }
        h = relu4(h);
        const float* w4r = W4 + (4 * j4) * D;
        #pragma unroll
        for (int qq = 0; qq < 4; ++qq) {
            const float hq = (qq == 0) ? h.x : (qq == 1) ? h.y : (qq == 2) ? h.z : h.w;
            #pragma unroll
            for (int d4 = 0; d4 < 4; ++d4)
                dl4[d4] = fma4(hq, ld4(w4r + qq * D + 4 * d4), dl4[d4]);
        }
    }
    float4* po = reinterpret_cast<float4*>(out + (size_t)idx * D);
    #pragma unroll
    for (int qq = 0; qq < 4; ++qq) {
        float4 v = dl4[qq];
        float4 pv = in4[qq];
        po[qq] = float4{pv.x + v.x, pv.y + v.y, pv.z + v.z, pv.w + v.w};
    }
}

}  // namespace

extern "C" void kernel_launch(void* const* d_in, const int* in_sizes, int n_in,
                              void* d_out, int out_size, void* d_ws, size_t ws_size,
                              hipStream_t stream) {
    const float* particles = (const float*)d_in[0];
    const int*   senders   = (const int*)d_in[1];
    const int*   receivers = (const int*)d_in[2];
    const float* W1 = (const float*)d_in[3];
    const float* b1 = (const float*)d_in[4];
    const float* W2 = (const float*)d_in[5];
    const float* b2 = (const float*)d_in[6];
    const float* W3 = (const float*)d_in[7];
    const float* b3 = (const float*)d_in[8];
    const float* W4 = (const float*)d_in[9];
    const float* b4 = (const float*)d_in[10];
    float* out = (float*)d_out;

    // workspace layout (256-B aligned slices)
    char* ws = (char*)d_ws;
    size_t off = 0;
    auto take = [&](size_t bytes) -> char* {
        char* p = ws + off;
        off = (off + bytes + 255) & ~(size_t)255;
        return p;
    };
    int*   cnt     = (int*)  take((size_t)N * 4);
    int*   done    = (int*)  take(4);            // contiguous after cnt
    int*   pos     = (int*)  take((size_t)N * 4);
    int2*  sr      = (int2*) take((size_t)E * 8);
    float* rel     = (float*)take((size_t)B * N * R * 4);
    short* w1p     = (short*)take((size_t)4 * 64 * 8 * 2);
    short* w2p     = (short*)take((size_t)4 * 64 * 8 * 2);
    short* w3p     = (short*)take((size_t)8 * 64 * 8 * 2);
    short* w4p     = (short*)take((size_t)2 * 64 * 8 * 2);
    const bool fast = (off <= ws_size);

    if (fast) {
        // one memset covers cnt (N*4 bytes) + done (4 bytes right after)
        hipMemsetAsync(cnt, 0, (size_t)N * 4 + 4, stream);
        histscan_prepack_kernel<<<1153, 256, 0, stream>>>(
            receivers, cnt, done, pos,
            W1, W2, W3, W4, w1p, w2p, w3p, w4p, (float4*)rel);
        scatter_kernel<<<E / 256, 256, 0, stream>>>(senders, receivers, pos, sr);
        edge_mfma_kernel<<<(B * E) / 256, 256, 0, stream>>>(
            particles, sr, w1p, b1, w2p, b2, rel);
        node_mfma_kernel<<<(B * N / 16) / 4, 256, 0, stream>>>(
            particles, rel, w3p, b3, w4p, b4, out);
    } else {
        float* rel0 = (float*)d_ws;
        hipMemsetAsync(rel0, 0, (size_t)B * N * R * 4, stream);
        edge_atomic_kernel<<<(B * E) / 256, 256, 0, stream>>>(
            particles, senders, receivers, W1, b1, W2, b2, rel0);
        node_valu_kernel<<<(B * N) / 256, 256, 0, stream>>>(
            particles, rel0, W3, b3, W4, b4, out);
    }
}

// Round 6
// 139.756 us; speedup vs baseline: 4.6381x; 1.1151x over previous
//
#include <hip/hip_runtime.h>
#include <hip/hip_bf16.h>

namespace {

constexpr int B = 4;
constexpr int N = 8192;     // 2^13
constexpr int D = 16;
constexpr int R = 32;
constexpr int H = 64;
constexpr int E = 262144;   // 2^18

typedef __attribute__((ext_vector_type(8))) short short8;   // 8 x bf16 (4 VGPRs)
typedef __attribute__((ext_vector_type(4))) short short4v;  // 4 x bf16 (2 VGPRs)
typedef __attribute__((ext_vector_type(4))) float f32x4;    // MFMA accumulator

__device__ __forceinline__ float4 ld4(const float* p) {
    return *reinterpret_cast<const float4*>(p);
}
__device__ __forceinline__ float4 fma4(float a, float4 w, float4 c) {
    return float4{fmaf(a, w.x, c.x), fmaf(a, w.y, c.y),
                  fmaf(a, w.z, c.z), fmaf(a, w.w, c.w)};
}
__device__ __forceinline__ float4 relu4(float4 v) {
    return float4{fmaxf(v.x, 0.f), fmaxf(v.y, 0.f), fmaxf(v.z, 0.f), fmaxf(v.w, 0.f)};
}
__device__ __forceinline__ short bf16s(float f) {
    __hip_bfloat16 h = __float2bfloat16(f);   // RNE
    return __builtin_bit_cast(short, h);
}
__device__ __forceinline__ short8 pack8(float4 a, float4 b) {
    short8 o;
    o[0] = bf16s(a.x); o[1] = bf16s(a.y); o[2] = bf16s(a.z); o[3] = bf16s(a.w);
    o[4] = bf16s(b.x); o[5] = bf16s(b.y); o[6] = bf16s(b.z); o[7] = bf16s(b.w);
    return o;
}
// relu + pack 4 accumulator floats into 4 bf16
__device__ __forceinline__ short4v pack4_relu(f32x4 c) {
    short4v o;
    o[0] = bf16s(fmaxf(c[0], 0.f)); o[1] = bf16s(fmaxf(c[1], 0.f));
    o[2] = bf16s(fmaxf(c[2], 0.f)); o[3] = bf16s(fmaxf(c[3], 0.f));
    return o;
}
// concat two packed short4v into an MFMA A/B fragment (pure register op)
__device__ __forceinline__ short8 cat44(short4v a, short4v b) {
    int2 ia = __builtin_bit_cast(int2, a);
    int2 ib = __builtin_bit_cast(int2, b);
    int4 v{ia.x, ia.y, ib.x, ib.y};
    return __builtin_bit_cast(short8, v);
}
// extract position i (0..31) from 4x int4 of packed bf16 (i must be compile-time)
__device__ __forceinline__ float red_get(const int4* uu, int i) {
    const int wsel = i >> 1;
    const int4 v = uu[wsel >> 2];
    const int word = (wsel & 3) == 0 ? v.x : (wsel & 3) == 1 ? v.y
                   : (wsel & 3) == 2 ? v.z : v.w;
    return (i & 1) ? __builtin_bit_cast(float, word & 0xffff0000)
                   : __builtin_bit_cast(float, (unsigned)word << 16);
}

constexpr int RED_S = 264;   // red stride in shorts; %8==0 keeps b128 reads 16B-aligned

// hidden-permutation for layer-2/4 row packing (R5-verified): the C/D accumulator
// of layer 1/3 (lane q*16+l15, tile mt, reg rg = hidden mt*16+q*4+rg) is consumed
// DIRECTLY as the next layer's A/B fragment (k = q*8+j) iff row k sources hidden
//   rho(k) = 32*(k>>5) + ((k>>2)&1)*16 + ((k>>3)&3)*4 + (k&3)
// Then h0 = concat(tile0,tile1), h1 = concat(tile2,tile3): NO LDS transpose.

__device__ __forceinline__ void prepack_w12(
    int t, const float* __restrict__ W1, const float* __restrict__ W2,
    short* __restrict__ w1p, short* __restrict__ w2p)
{
    // A/B-frag mapping (mfma_f32_16x16x32_bf16, verified m89):
    //   m|n = lane&15, k = (lane>>4)*8 + j  (identical for A and B)
    for (int i = t; i < 4 * 64 * 8; i += 256) {
        int j = i & 7, lane = (i >> 3) & 63, ct = i >> 9;
        int k = (lane >> 4) * 8 + j, n = ct * 16 + (lane & 15);
        w1p[i] = bf16s(W1[k * H + n]);
    }
    for (int i = t; i < 4 * 64 * 8; i += 256) {
        int j = i & 7, lane = (i >> 3) & 63, idx = i >> 9;
        int ct = idx >> 1, kc = idx & 1;
        // rho-remapped row: was kc*32 + (lane>>4)*8 + j
        int k = kc * 32 + (j >> 2) * 16 + ((lane >> 4) & 3) * 4 + (j & 3);
        int f = ct * 16 + (lane & 15);
        w2p[i] = bf16s(W2[k * R + f]);
    }
}
__device__ __forceinline__ void prepack_w34(
    int t, const float* __restrict__ W3, const float* __restrict__ W4,
    short* __restrict__ w3p, short* __restrict__ w4p)
{
    for (int i = t; i < 8 * 64 * 8; i += 256) {
        int j = i & 7, lane = (i >> 3) & 63, idx = i >> 9;
        int ct = idx >> 1, kc = idx & 1;
        int k = kc * 32 + (lane >> 4) * 8 + j, n = ct * 16 + (lane & 15);
        w3p[i] = (k < D + R) ? bf16s(W3[k * H + n]) : (short)0;
    }
    for (int i = t; i < 2 * 64 * 8; i += 256) {
        int j = i & 7, lane = (i >> 3) & 63, kc = i >> 9;
        // rho-remapped row: was kc*32 + (lane>>4)*8 + j
        int k = kc * 32 + (j >> 2) * 16 + ((lane >> 4) & 3) * 4 + (j & 3);
        int d = lane & 15;
        w4p[i] = bf16s(W4[k * D + d]);
    }
}

// ---------------------------------------------------------------------------
// Dispatch 2: histogram (blocks 0..1023), weight prepack (block 1024),
//             rel zero (blocks 1025..1152).  (R0-proven structure)
// ---------------------------------------------------------------------------
__global__ __launch_bounds__(256) void hist_prepack_kernel(
    const int* __restrict__ receivers, int* __restrict__ cnt,
    const float* __restrict__ W1, const float* __restrict__ W2,
    const float* __restrict__ W3, const float* __restrict__ W4,
    short* __restrict__ w1p, short* __restrict__ w2p,
    short* __restrict__ w3p, short* __restrict__ w4p,
    float4* __restrict__ relz)
{
    if (blockIdx.x < 1024) {
        int e = blockIdx.x * 256 + threadIdx.x;
        atomicAdd(cnt + receivers[e], 1);
        return;
    }
    if (blockIdx.x >= 1025) {
        const int base = (blockIdx.x - 1025) * 256 + threadIdx.x;
        #pragma unroll
        for (int i = 0; i < 8; ++i)
            relz[base + i * 32768] = float4{0.f, 0.f, 0.f, 0.f};
        return;
    }
    prepack_w12(threadIdx.x, W1, W2, w1p, w2p);
    prepack_w34(threadIdx.x, W3, W4, w3p, w4p);
}

// ---------------------------------------------------------------------------
// Dispatch 3: exclusive scan of 8192 counts (one block, plain loads — the
// dispatch boundary provides coherence; R0-proven, ~2 µs).
// ---------------------------------------------------------------------------
__global__ __launch_bounds__(1024) void scan_kernel(
    const int* __restrict__ cnt, int* __restrict__ pos)
{
    __shared__ int wtot[16];
    const int t = threadIdx.x;
    const int lane = t & 63;
    int local[8];
    int s = 0;
    #pragma unroll
    for (int i = 0; i < 8; ++i) { local[i] = cnt[t * 8 + i]; s += local[i]; }
    int incl = s;
    #pragma unroll
    for (int d = 1; d < 64; d <<= 1) {
        int v = __shfl_up(incl, d, 64);
        if (lane >= d) incl += v;
    }
    if (lane == 63) wtot[t >> 6] = incl;
    __syncthreads();
    int base = incl - s;
    const int wv = t >> 6;
    #pragma unroll
    for (int i = 0; i < 16; ++i) base += (i < wv) ? wtot[i] : 0;
    #pragma unroll
    for (int i = 0; i < 8; ++i) {
        pos[t * 8 + i] = base;
        base += local[i];
    }
}

// ---------------------------------------------------------------------------
// Dispatch 4: scatter edges into receiver-sorted order.
// ---------------------------------------------------------------------------
__global__ __launch_bounds__(256) void scatter_kernel(
    const int* __restrict__ senders, const int* __restrict__ receivers,
    int* __restrict__ pos, int2* __restrict__ sr)
{
    int e = blockIdx.x * 256 + threadIdx.x;
    if (e < E) {
        int r = receivers[e];
        int p = atomicAdd(pos + r, 1);
        sr[p] = int2{senders[e], r};
    }
}

// ---------------------------------------------------------------------------
// Dispatch 5: MFMA edge MLP + two-stage segmented reduction (4096 blocks).
// rho-remap: no LDS transpose (R5-verified). Two-stage reduction (R4-verified):
// only first/last receivers of a window can straddle blocks -> atomicAdd;
// interior receivers -> plain stores into pre-zeroed rel.
// ---------------------------------------------------------------------------
__global__ __launch_bounds__(256, 4) void edge_mfma_kernel(
    const float* __restrict__ particles,
    const int2*  __restrict__ sr,
    const short* __restrict__ w1p, const float* __restrict__ b1,
    const short* __restrict__ w2p, const float* __restrict__ b2,
    float* __restrict__ rel)
{
    __shared__ short red[R * RED_S];          // [f][pos] bf16, stride 264 (16.9 KB)
    __shared__ int   rs[256];
    __shared__ float pre[8][33];              // first-segment sum per (group,feat)
    __shared__ float suf[8][33];              // last-segment sum per (group,feat)
    __shared__ int   kcnt[8];                 // segments per group

    const int tid  = threadIdx.x;
    const int lane = tid & 63;
    const int w    = tid >> 6;
    const int b    = blockIdx.x >> 10;        // 1024 blocks per batch
    const int p0   = (blockIdx.x & 1023) * 256;
    const int l15  = lane & 15;
    const int q    = lane >> 4;

    const int2 srv = sr[p0 + tid];
    rs[tid] = srv.y;

    // hoisted gather: distribute rows via shfl, issue all 8 dwordx4 loads up front
    float4 a0[4], a1[4];
    #pragma unroll
    for (int t = 0; t < 4; ++t) {
        int srow = __shfl(srv.x, t * 16 + l15);
        int rrow = __shfl(srv.y, t * 16 + l15);
        int row = (q < 2) ? srow : rrow;
        const float* src = particles + ((size_t)b * N + row) * D + (q & 1) * 8;
        a0[t] = ld4(src);
        a1[t] = ld4(src + 4);
    }

    // weight fragments (L2-hot, coalesced)
    short8 w1f[4], w2f[4];
    #pragma unroll
    for (int mt = 0; mt < 4; ++mt)
        w1f[mt] = *reinterpret_cast<const short8*>(w1p + (mt * 64 + lane) * 8);
    #pragma unroll
    for (int i = 0; i < 4; ++i)
        w2f[i] = *reinterpret_cast<const short8*>(w2p + (i * 64 + lane) * 8);

    f32x4 bias1[4];
    #pragma unroll
    for (int mt = 0; mt < 4; ++mt) {
        float4 t4 = ld4(b1 + mt * 16 + q * 4);
        bias1[mt] = f32x4{t4.x, t4.y, t4.z, t4.w};
    }
    const float bias2a = b2[l15];
    const float bias2b = b2[16 + l15];

    short8 af[4];
    #pragma unroll
    for (int t = 0; t < 4; ++t) af[t] = pack8(a0[t], a1[t]);

    #pragma unroll
    for (int t = 0; t < 4; ++t) {
        // layer1: 4 hidden m-tiles, K=32 -> packed bf16 kept in registers
        f32x4 c0 = __builtin_amdgcn_mfma_f32_16x16x32_bf16(w1f[0], af[t], bias1[0], 0, 0, 0);
        f32x4 c1 = __builtin_amdgcn_mfma_f32_16x16x32_bf16(w1f[1], af[t], bias1[1], 0, 0, 0);
        f32x4 c2 = __builtin_amdgcn_mfma_f32_16x16x32_bf16(w1f[2], af[t], bias1[2], 0, 0, 0);
        f32x4 c3 = __builtin_amdgcn_mfma_f32_16x16x32_bf16(w1f[3], af[t], bias1[3], 0, 0, 0);
        short8 h0 = cat44(pack4_relu(c0), pack4_relu(c1));   // k = 0..31 (rho rows)
        short8 h1 = cat44(pack4_relu(c2), pack4_relu(c3));   // k = 32..63

        // layer2: D2[edge][f], 2 f-tiles, K=64
        f32x4 r0 = {bias2a, bias2a, bias2a, bias2a};
        f32x4 r1 = {bias2b, bias2b, bias2b, bias2b};
        r0 = __builtin_amdgcn_mfma_f32_16x16x32_bf16(h0, w2f[0], r0, 0, 0, 0);
        r0 = __builtin_amdgcn_mfma_f32_16x16x32_bf16(h1, w2f[1], r0, 0, 0, 0);
        r1 = __builtin_amdgcn_mfma_f32_16x16x32_bf16(h0, w2f[2], r1, 0, 0, 0);
        r1 = __builtin_amdgcn_mfma_f32_16x16x32_bf16(h1, w2f[3], r1, 0, 0, 0);

        const int pb2 = w * 64 + t * 16 + q * 4;
        *reinterpret_cast<short4v*>(red + l15 * RED_S + pb2)        = pack4_relu(r0);
        *reinterpret_cast<short4v*>(red + (16 + l15) * RED_S + pb2) = pack4_relu(r1);
    }
    __syncthreads();

    // ---- stage 1: per-(group,feature) segmented partial sums ----
    const int g2 = tid >> 5;
    const int f  = tid & 31;
    const int gb = g2 * 32;
    float* relb = rel + (size_t)b * N * R;

    unsigned bmask = 0;
    int first;
    {
        int4 r4[8];
        #pragma unroll
        for (int i = 0; i < 8; ++i)
            r4[i] = *reinterpret_cast<const int4*>(rs + gb + 4 * i);
        first = r4[0].x;
        int prev = first;
        #pragma unroll
        for (int i = 1; i < 32; ++i) {
            const int4 v4 = r4[i >> 2];
            const int rr = (i & 3) == 0 ? v4.x : (i & 3) == 1 ? v4.y
                         : (i & 3) == 2 ? v4.z : v4.w;
            if (rr != prev) bmask |= (1u << i);
            prev = rr;
        }
    }
    if (f == 0) kcnt[g2] = __popc(bmask) + 1;

    int4 uu[4];
    #pragma unroll
    for (int i = 0; i < 4; ++i)
        uu[i] = *reinterpret_cast<const int4*>(red + f * RED_S + gb + 8 * i);

    {
        float acc = 0.f;
        int cur = first;
        int seg = 0;
        #pragma unroll
        for (int i = 0; i < 32; ++i) {
            if (bmask & (1u << i)) {
                if (seg == 0) pre[g2][f] = acc;
                else relb[(size_t)cur * R + f] = acc;   // interior complete receiver
                ++seg;
                acc = 0.f;
                cur = rs[gb + i];
            }
            acc += red_get(uu, i);
        }
        suf[g2][f] = acc;   // last segment (k==1: whole group; pre unwritten)
    }
    __syncthreads();

    // ---- stage 2: merge chains across groups (one thread per feature) ----
    if (tid < 32) {
        int   cur2 = rs[0];
        float a2   = 0.f;
        int   nfl  = 0;
        #pragma unroll
        for (int g = 0; g < 8; ++g) {
            const int   rf   = rs[g * 32];
            const int   rl   = rs[g * 32 + 31];
            const int   kk   = kcnt[g];
            const float sufv = suf[g][tid];
            if (kk == 1) {
                if (rf == cur2) a2 += sufv;
                else {
                    if (nfl == 0) atomicAdd(relb + (size_t)cur2 * R + tid, a2);
                    else          relb[(size_t)cur2 * R + tid] = a2;
                    ++nfl;
                    cur2 = rf; a2 = sufv;
                }
            } else {
                const float prev = pre[g][tid];
                if (rf == cur2) {
                    a2 += prev;
                    if (nfl == 0) atomicAdd(relb + (size_t)cur2 * R + tid, a2);
                    else          relb[(size_t)cur2 * R + tid] = a2;
                    ++nfl;
                } else {
                    if (nfl == 0) atomicAdd(relb + (size_t)cur2 * R + tid, a2);
                    else          relb[(size_t)cur2 * R + tid] = a2;
                    ++nfl;
                    relb[(size_t)rf * R + tid] = prev;   // complete receiver
                    ++nfl;
                }
                cur2 = rl; a2 = sufv;
            }
        }
        atomicAdd(relb + (size_t)cur2 * R + tid, a2);   // may span into next window
    }
}

// ---------------------------------------------------------------------------
// Dispatch 6: MFMA node MLP, one 16-node tile per wave. Zero LDS (rho-remap).
// ---------------------------------------------------------------------------
__global__ __launch_bounds__(256, 4) void node_mfma_kernel(
    const float* __restrict__ particles,
    const float* __restrict__ rel,
    const short* __restrict__ w3p, const float* __restrict__ b3,
    const short* __restrict__ w4p, const float* __restrict__ b4,
    float* __restrict__ out)
{
    const int tid  = threadIdx.x;
    const int lane = tid & 63;
    const int w    = tid >> 6;
    const int tile = blockIdx.x * 4 + w;        // [0, B*N/16)
    const int b    = tile >> 9;                 // 512 tiles per batch
    const int l15  = lane & 15;
    const int q    = lane >> 4;
    const int node = (tile & 511) * 16 + l15;

    const float* prow = particles + ((size_t)b * N + node) * D;
    const float* rrow = rel + ((size_t)b * N + node) * R;

    const float* src0 = (q < 2) ? (prow + (q & 1) * 8) : (rrow + (q & 1) * 8);
    float4 c0a = ld4(src0), c0b = ld4(src0 + 4);
    float4 c1a = {0.f, 0.f, 0.f, 0.f}, c1b = {0.f, 0.f, 0.f, 0.f};
    if (q < 2) { c1a = ld4(rrow + 16 + q * 8); c1b = ld4(rrow + 20 + q * 8); }

    short8 w3f[8], w4f[2];
    #pragma unroll
    for (int i = 0; i < 8; ++i)
        w3f[i] = *reinterpret_cast<const short8*>(w3p + (i * 64 + lane) * 8);
    #pragma unroll
    for (int i = 0; i < 2; ++i)
        w4f[i] = *reinterpret_cast<const short8*>(w4p + (i * 64 + lane) * 8);

    f32x4 bias3[4];
    #pragma unroll
    for (int mt = 0; mt < 4; ++mt) {
        float4 t4 = ld4(b3 + mt * 16 + q * 4);
        bias3[mt] = f32x4{t4.x, t4.y, t4.z, t4.w};
    }
    f32x4 bias4;
    { float4 t4 = ld4(b4 + q * 4); bias4 = f32x4{t4.x, t4.y, t4.z, t4.w}; }

    short8 a0 = pack8(c0a, c0b);
    short8 a1 = pack8(c1a, c1b);

    // layer3: 4 hidden m-tiles, K=48 (padded 64) -> packed in registers
    f32x4 c0 = bias3[0], c1 = bias3[1], c2 = bias3[2], c3 = bias3[3];
    c0 = __builtin_amdgcn_mfma_f32_16x16x32_bf16(w3f[0], a0, c0, 0, 0, 0);
    c0 = __builtin_amdgcn_mfma_f32_16x16x32_bf16(w3f[1], a1, c0, 0, 0, 0);
    c1 = __builtin_amdgcn_mfma_f32_16x16x32_bf16(w3f[2], a0, c1, 0, 0, 0);
    c1 = __builtin_amdgcn_mfma_f32_16x16x32_bf16(w3f[3], a1, c1, 0, 0, 0);
    c2 = __builtin_amdgcn_mfma_f32_16x16x32_bf16(w3f[4], a0, c2, 0, 0, 0);
    c2 = __builtin_amdgcn_mfma_f32_16x16x32_bf16(w3f[5], a1, c2, 0, 0, 0);
    c3 = __builtin_amdgcn_mfma_f32_16x16x32_bf16(w3f[6], a0, c3, 0, 0, 0);
    c3 = __builtin_amdgcn_mfma_f32_16x16x32_bf16(w3f[7], a1, c3, 0, 0, 0);
    short8 h0 = cat44(pack4_relu(c0), pack4_relu(c1));   // k = 0..31 (rho rows)
    short8 h1 = cat44(pack4_relu(c2), pack4_relu(c3));   // k = 32..63

    f32x4 r = bias4;
    r = __builtin_amdgcn_mfma_f32_16x16x32_bf16(w4f[0], h0, r, 0, 0, 0);
    r = __builtin_amdgcn_mfma_f32_16x16x32_bf16(w4f[1], h1, r, 0, 0, 0);

    float4 pv = ld4(prow + q * 4);
    float4* po = reinterpret_cast<float4*>(out + ((size_t)b * N + node) * D + q * 4);
    *po = float4{pv.x + r[0], pv.y + r[1], pv.z + r[2], pv.w + r[3]};
}

// ---------- fallback path (fp32, correctness backstop) ----------

__global__ __launch_bounds__(256, 2) void edge_atomic_kernel(
    const float* __restrict__ particles,
    const int*   __restrict__ senders,
    const int*   __restrict__ receivers,
    const float* __restrict__ W1, const float* __restrict__ b1,
    const float* __restrict__ W2, const float* __restrict__ b2,
    float* __restrict__ rel)
{
    const int idx = blockIdx.x * 256 + threadIdx.x;
    const int b = idx >> 18;
    const int e = idx & (E - 1);
    const int s = senders[e];
    const int r = receivers[e];

    float4 ein4[8];
    {
        const float4* ps = reinterpret_cast<const float4*>(particles + ((size_t)b * N + s) * D);
        const float4* pr = reinterpret_cast<const float4*>(particles + ((size_t)b * N + r) * D);
        #pragma unroll
        for (int qq = 0; qq < 4; ++qq) ein4[qq] = ps[qq];
        #pragma unroll
        for (int qq = 0; qq < 4; ++qq) ein4[4 + qq] = pr[qq];
    }
    float4 rf4[8];
    #pragma unroll
    for (int qq = 0; qq < 8; ++qq) rf4[qq] = ld4(b2 + 4 * qq);

    for (int j4 = 0; j4 < H / 4; ++j4) {
        float4 h = ld4(b1 + 4 * j4);
        const float* w1c = W1 + 4 * j4;
        #pragma unroll
        for (int kv = 0; kv < 8; ++kv) {
            const float4 ev = ein4[kv];
            h = fma4(ev.x, ld4(w1c + (4 * kv + 0) * H), h);
            h = fma4(ev.y, ld4(w1c + (4 * kv + 1) * H), h);
            h = fma4(ev.z, ld4(w1c + (4 * kv + 2) * H), h);
            h = fma4(ev.w, ld4(w1c + (4 * kv + 3) * H), h);
        }
        h = relu4(h);
        const float* w2r = W2 + (4 * j4) * R;
        #pragma unroll
        for (int qq = 0; qq < 4; ++qq) {
            const float hq = (qq == 0) ? h.x : (qq == 1) ? h.y : (qq == 2) ? h.z : h.w;
            #pragma unroll
            for (int r4 = 0; r4 < 8; ++r4)
                rf4[r4] = fma4(hq, ld4(w2r + qq * R + 4 * r4), rf4[r4]);
        }
    }
    float* dst = rel + ((size_t)b * N + r) * R;
    #pragma unroll
    for (int r4 = 0; r4 < 8; ++r4) {
        float4 v = relu4(rf4[r4]);
        atomicAdd(dst + 4 * r4 + 0, v.x);
        atomicAdd(dst + 4 * r4 + 1, v.y);
        atomicAdd(dst + 4 * r4 + 2, v.z);
        atomicAdd(dst + 4 * r4 + 3, v.w);
    }
}

__global__ __launch_bounds__(256, 2) void node_valu_kernel(
    const float* __restrict__ particles,
    const float* __restrict__ rel,
    const float* __restrict__ W3, const float* __restrict__ b3,
    const float* __restrict__ W4, const float* __restrict__ b4,
    float* __restrict__ out)
{
    const int idx = blockIdx.x * 256 + threadIdx.x;
    float4 in4[12];
    {
        const float4* pp = reinterpret_cast<const float4*>(particles + (size_t)idx * D);
        #pragma unroll
        for (int qq = 0; qq < 4; ++qq) in4[qq] = pp[qq];
        const float4* pr = reinterpret_cast<const float4*>(rel + (size_t)idx * R);
        #pragma unroll
        for (int qq = 0; qq < 8; ++qq) in4[4 + qq] = pr[qq];
    }
    float4 dl4[4];
    #pragma unroll
    for (int qq = 0; qq < 4; ++qq) dl4[qq] = ld4(b4 + 4 * qq);

    for (int j4 = 0; j4 < H / 4; ++j4) {
        float4 h = ld4(b3 + 4 * j4);
        const float* w3c = W3 + 4 * j4;
        #pragma unroll
        for (int kv = 0; kv < 12; ++kv) {
            const float4 ev = in4[kv];
            h = fma4(ev.x, ld4(w3c + (4 * kv + 0) * H), h);
            h = fma4(ev.y, ld4(w3c + (4 * kv + 1) * H), h);
            h = fma4(ev.z, ld4(w3c + (4 * kv + 2) * H), h);
            h = fma4(ev.w, ld4(w3c + (4 * kv + 3) * H), h);
        }
        h = relu4(h);
        const float* w4r = W4 + (4 * j4) * D;
        #pragma unroll
        for (int qq = 0; qq < 4; ++qq) {
            const float hq = (qq == 0) ? h.x : (qq == 1) ? h.y : (qq == 2) ? h.z : h.w;
            #pragma unroll
            for (int d4 = 0; d4 < 4; ++d4)
                dl4[d4] = fma4(hq, ld4(w4r + qq * D + 4 * d4), dl4[d4]);
        }
    }
    float4* po = reinterpret_cast<float4*>(out + (size_t)idx * D);
    #pragma unroll
    for (int qq = 0; qq < 4; ++qq) {
        float4 v = dl4[qq];
        float4 pv = in4[qq];
        po[qq] = float4{pv.x + v.x, pv.y + v.y, pv.z + v.z, pv.w + v.w};
    }
}

}  // namespace

extern "C" void kernel_launch(void* const* d_in, const int* in_sizes, int n_in,
                              void* d_out, int out_size, void* d_ws, size_t ws_size,
                              hipStream_t stream) {
    const float* particles = (const float*)d_in[0];
    const int*   senders   = (const int*)d_in[1];
    const int*   receivers = (const int*)d_in[2];
    const float* W1 = (const float*)d_in[3];
    const float* b1 = (const float*)d_in[4];
    const float* W2 = (const float*)d_in[5];
    const float* b2 = (const float*)d_in[6];
    const float* W3 = (const float*)d_in[7];
    const float* b3 = (const float*)d_in[8];
    const float* W4 = (const float*)d_in[9];
    const float* b4 = (const float*)d_in[10];
    float* out = (float*)d_out;

    // workspace layout (256-B aligned slices)
    char* ws = (char*)d_ws;
    size_t off = 0;
    auto take = [&](size_t bytes) -> char* {
        char* p = ws + off;
        off = (off + bytes + 255) & ~(size_t)255;
        return p;
    };
    int*   cnt     = (int*)  take((size_t)N * 4);
    int*   pos     = (int*)  take((size_t)N * 4);
    int2*  sr      = (int2*) take((size_t)E * 8);
    float* rel     = (float*)take((size_t)B * N * R * 4);
    short* w1p     = (short*)take((size_t)4 * 64 * 8 * 2);
    short* w2p     = (short*)take((size_t)4 * 64 * 8 * 2);
    short* w3p     = (short*)take((size_t)8 * 64 * 8 * 2);
    short* w4p     = (short*)take((size_t)2 * 64 * 8 * 2);
    const bool fast = (off <= ws_size);

    if (fast) {
        hipMemsetAsync(cnt, 0, (size_t)N * 4, stream);
        hist_prepack_kernel<<<1153, 256, 0, stream>>>(
            receivers, cnt, W1, W2, W3, W4, w1p, w2p, w3p, w4p, (float4*)rel);
        scan_kernel<<<1, 1024, 0, stream>>>(cnt, pos);
        scatter_kernel<<<E / 256, 256, 0, stream>>>(senders, receivers, pos, sr);
        edge_mfma_kernel<<<(B * E) / 256, 256, 0, stream>>>(
            particles, sr, w1p, b1, w2p, b2, rel);
        node_mfma_kernel<<<(B * N / 16) / 4, 256, 0, stream>>>(
            particles, rel, w3p, b3, w4p, b4, out);
    } else {
        float* rel0 = (float*)d_ws;
        hipMemsetAsync(rel0, 0, (size_t)B * N * R * 4, stream);
        edge_atomic_kernel<<<(B * E) / 256, 256, 0, stream>>>(
            particles, senders, receivers, W1, b1, W2, b2, rel0);
        node_valu_kernel<<<(B * N) / 256, 256, 0, stream>>>(
            particles, rel0, W3, b3, W4, b4, out);
    }
}